// Round 5
// baseline (179.194 us; speedup 1.0000x reference)
//
#include <hip/hip_runtime.h>

// Problem constants (match reference)
#define B_    128
#define G_    12000
#define K_    512
#define H_    64

#define CCH   160      // column chunks
#define CROWS 75       // rows per chunk (160*75 = 12000)
#define CW    12       // max nnz per (column, chunk)  Poisson(1.5): P(>12)~2e-9
#define RW    32       // max nnz per row              Poisson(10.24): P(>32)~5e-9
#define QSP   8        // k_gather k-split
#define QCH   (CCH / QSP)   // 20 chunks per split

// ---------------- k_trans: [B,G] ctl/dt -> packed xT[G][B] float2 ----------
__global__ void k_trans(const float* __restrict__ ctl, const float* __restrict__ dt,
                        float2* __restrict__ xT) {
    __shared__ float tc[32][33];
    __shared__ float td[32][33];
    int g0 = blockIdx.x * 32, b0 = blockIdx.y * 32;
    int tx = threadIdx.x, ty = threadIdx.y;
#pragma unroll
    for (int j = 0; j < 4; ++j) {
        tc[ty + 8 * j][tx] = ctl[(size_t)(b0 + ty + 8 * j) * G_ + g0 + tx];
        td[ty + 8 * j][tx] = dt [(size_t)(b0 + ty + 8 * j) * G_ + g0 + tx];
    }
    __syncthreads();
#pragma unroll
    for (int j = 0; j < 4; ++j)
        xT[(size_t)(g0 + ty + 8 * j) * B_ + b0 + tx] =
            make_float2(tc[tx][ty + 8 * j], td[tx][ty + 8 * j]);
}

// ---------------- k_msetup: ONE M pass -> column-ELL + row-ELL + cvec ------
__global__ __launch_bounds__(512) void k_msetup(const float* __restrict__ M,
        int* __restrict__ ccnt, int* __restrict__ cell_ell,
        int* __restrict__ rcnt, int* __restrict__ rell,
        const int* __restrict__ cidx, const float* __restrict__ cemb,
        const float* __restrict__ W_out, const float* __restrict__ b_out,
        float* __restrict__ cvec) {
    int c = blockIdx.x;
    int tid = threadIdx.x;
    if (c == CCH) {                       // tail block: cvec[b]
        if (tid < B_) {
            int ci = cidx[tid];
            float acc = b_out[0];
#pragma unroll 8
            for (int h = 0; h < H_; ++h)
                acc = fmaf(cemb[ci * H_ + h], W_out[h], acc);
            cvec[tid] = acc;
        }
        return;
    }
    // phase A: column ELL (thread k scans its column over this chunk's rows)
    {
        int k = tid;
        const float* Mp = M + (size_t)c * CROWS * K_ + k;
        int* el = cell_ell + ((size_t)c * K_ + k) * CW;
        int cnt = 0;
        for (int r = 0; r < CROWS; ++r) {
            if (Mp[(size_t)r * K_] != 0.0f) {
                if (cnt < CW) el[cnt] = c * CROWS + r;
                ++cnt;
            }
        }
        ccnt[c * K_ + k] = (cnt <= CW) ? cnt : CW;
    }
    // phase B: row ELL, one wave per row (rows re-read from L2)
    {
        int w = tid >> 6, lane = tid & 63;
        for (int r = w; r < CROWS; r += 8) {
            int g = c * CROWS + r;
            const float* Mp = M + (size_t)g * K_;
            int base = 0, outb = g * RW;
#pragma unroll
            for (int c0 = 0; c0 < K_; c0 += 64) {
                float v = Mp[c0 + lane];
                unsigned long long mask = __ballot(v != 0.0f);
                int before = __popcll(mask & ((1ull << lane) - 1ull));
                if (v != 0.0f) {
                    int o = base + before;
                    if (o < RW) rell[outb + o] = c0 + lane;
                }
                base += __popcll(mask);
            }
            if (lane == 0) rcnt[g] = (base <= RW) ? base : RW;
        }
    }
}

// ---------------- k_at: AT[l][k] = A[k][l];  U2 = 0.09*AT + 0.1*I ----------
__global__ void k_at(const float* __restrict__ A, float* __restrict__ AT,
                     float* __restrict__ U2) {
    __shared__ float t[32][33];
    int x0 = blockIdx.x * 32, y0 = blockIdx.y * 32;
    int tx = threadIdx.x, ty = threadIdx.y;
#pragma unroll
    for (int j = 0; j < 4; ++j)
        t[ty + 8 * j][tx] = A[(size_t)(y0 + ty + 8 * j) * K_ + x0 + tx];
    __syncthreads();
#pragma unroll
    for (int j = 0; j < 4; ++j) {
        int row = x0 + ty + 8 * j, col = y0 + tx;
        float v = t[tx][ty + 8 * j];
        AT[(size_t)row * K_ + col] = v;
        U2[(size_t)row * K_ + col] = 0.09f * v + (row == col ? 0.1f : 0.0f);
    }
}

// ---------------- mm body: O = alpha*Aop*Bop + beta*Cop; opt O2 = O + Dop ---
__device__ __forceinline__ void mm_body(const float* __restrict__ Aop,
        const float* __restrict__ Bop, const float* __restrict__ Cop,
        const float* __restrict__ Dop, float alpha, float beta,
        float* __restrict__ O, float* __restrict__ O2) {
    __shared__ __align__(16) float Xa[32][68];
    __shared__ __align__(16) float Xb[64][36];
    int k0 = blockIdx.x * 32, l0 = blockIdx.y * 32;
    int tid = threadIdx.x;
    int kg = tid & 15, lg = tid >> 4;
    float acc[2][2] = {};
    for (int jj = 0; jj < K_; jj += 64) {
#pragma unroll
        for (int i = 0; i < 2; ++i) {
            int lin = tid + i * 256;
            int r = lin >> 4, c4 = lin & 15;
            *(float4*)&Xa[r][c4 * 4] =
                *(const float4*)&Aop[(size_t)(l0 + r) * K_ + jj + c4 * 4];
        }
#pragma unroll
        for (int i = 0; i < 2; ++i) {
            int lin = tid + i * 256;
            int r = lin >> 3, c4 = lin & 7;
            *(float4*)&Xb[r][c4 * 4] =
                *(const float4*)&Bop[(size_t)(jj + r) * K_ + k0 + c4 * 4];
        }
        __syncthreads();
#pragma unroll 8
        for (int j = 0; j < 64; ++j) {
            float xa0 = Xa[lg * 2][j], xa1 = Xa[lg * 2 + 1][j];
            float xb0 = Xb[j][kg * 2], xb1 = Xb[j][kg * 2 + 1];
            acc[0][0] = fmaf(xa0, xb0, acc[0][0]);
            acc[0][1] = fmaf(xa0, xb1, acc[0][1]);
            acc[1][0] = fmaf(xa1, xb0, acc[1][0]);
            acc[1][1] = fmaf(xa1, xb1, acc[1][1]);
        }
        __syncthreads();
    }
#pragma unroll
    for (int i = 0; i < 2; ++i) {
        size_t idx = (size_t)(l0 + lg * 2 + i) * K_ + k0 + kg * 2;
        float2 v;
        v.x = alpha * acc[i][0];
        v.y = alpha * acc[i][1];
        if (beta != 0.0f) {
            float2 cc = *(const float2*)&Cop[idx];
            v.x = fmaf(beta, cc.x, v.x);
            v.y = fmaf(beta, cc.y, v.y);
        }
        *(float2*)&O[idx] = v;
        if (O2) {
            float2 dd = *(const float2*)&Dop[idx];
            float2 w2; w2.x = v.x + dd.x; w2.y = v.y + dd.y;
            *(float2*)&O2[idx] = w2;
        }
    }
}

__global__ __launch_bounds__(256) void k_mmg(const float* Aop, const float* Bop,
        const float* Cop, const float* Dop, float alpha, float beta,
        float* O, float* O2) {
    mm_body(Aop, Bop, Cop, Dop, alpha, beta, O, O2);
}

// fused pair: blockIdx.z selects product (two independent matmuls, one launch)
__global__ __launch_bounds__(256) void k_mmp(
        const float* A0, const float* B0, const float* C0, float beta0, float* O0,
        const float* A1, const float* B1, const float* C1, float beta1, float* O1) {
    if (blockIdx.z == 0) mm_body(A0, B0, C0, nullptr, 1.0f, beta0, O0, nullptr);
    else                 mm_body(A1, B1, C1, nullptr, 1.0f, beta1, O1, nullptr);
}

// ---------------- k_gather: 8-way split sparse aggregation, pipelined ------
__global__ __launch_bounds__(128) void k_gather(
        const int* __restrict__ ccnt, const int4* __restrict__ cell_ell4,
        const float2* __restrict__ xT,
        float2* __restrict__ pacc, int* __restrict__ pdeg) {
    int k = blockIdx.x, q = blockIdx.y;
    int bq = threadIdx.x;
    int c0 = q * QCH, c1 = c0 + QCH;
    float a0 = 0.f, a1 = 0.f;
    int deg = 0;
    // prefetch chunk c0's list (wave-uniform -> scalar loads)
    int n_nxt = ccnt[c0 * K_ + k];
    size_t base = ((size_t)c0 * K_ + k) * 3;
    int4 La = cell_ell4[base], Lb = cell_ell4[base + 1], Lc = cell_ell4[base + 2];
    for (int c = c0; c < c1; ++c) {
        int n = n_nxt;
        int idx[12] = {La.x, La.y, La.z, La.w, Lb.x, Lb.y, Lb.z, Lb.w,
                       Lc.x, Lc.y, Lc.z, Lc.w};
        if (c + 1 < c1) {                 // prefetch next chunk's list
            n_nxt = ccnt[(c + 1) * K_ + k];
            size_t nb = ((size_t)(c + 1) * K_ + k) * 3;
            La = cell_ell4[nb]; Lb = cell_ell4[nb + 1]; Lc = cell_ell4[nb + 2];
        }
        deg += n;
#pragma unroll
        for (int j = 0; j < CW; ++j) {
            if (j < n) {                  // n is wave-uniform
                float2 v = xT[(size_t)idx[j] * B_ + bq];
                a0 += v.x; a1 += v.y;
            }
        }
    }
    pacc[((size_t)q * K_ + k) * B_ + bq] = make_float2(a0, a1);
    if (bq == 0) pdeg[q * K_ + k] = deg;
}

// ---------------- k_smlp: combine partials + fused MLP -> s[k][b] ----------
__global__ __launch_bounds__(256) void k_smlp(const float2* __restrict__ pacc,
        const int* __restrict__ pdeg,
        const float* __restrict__ W_in, const float* __restrict__ b_in,
        const float* __restrict__ W_out, float* __restrict__ sout) {
    int idx = blockIdx.x * 256 + threadIdx.x;    // 65536 = K*B
    int k = idx >> 7, bq = idx & 127;
    float a0 = 0.f, a1 = 0.f;
    int deg = 0;
#pragma unroll
    for (int q = 0; q < QSP; ++q) {
        float2 v = pacc[((size_t)q * K_ + k) * B_ + bq];
        a0 += v.x; a1 += v.y;
        deg += pdeg[q * K_ + k];
    }
    float inv = 1.0f / fmaxf((float)deg, 1.0f);
    float x0 = a0 * inv, x1 = a1 * inv;
    float s = 0.f;
#pragma unroll 8
    for (int h = 0; h < H_; ++h) {
        float v = fmaf(x0, W_in[h], fmaf(x1, W_in[H_ + h], b_in[h]));
        v = fmaxf(v, 0.f);
        s = fmaf(v, W_out[h], s);
    }
    sout[k * B_ + bq] = s;
}

// ---------------- k_panel: out = c * W z + d * add   ([K][B]) --------------
__global__ __launch_bounds__(1024) void k_panel(const float* __restrict__ W,
        const float* __restrict__ zin, const float* __restrict__ addv,
        float c, float d, float* __restrict__ zout) {
    __shared__ __align__(16) float Wr[2 * K_];
    __shared__ float red[8][2][128];
    int tid = threadIdx.x;
    int l0 = blockIdx.x * 2;
    if (tid < 256)
        ((float4*)Wr)[tid] = ((const float4*)&W[(size_t)l0 * K_])[tid];
    __syncthreads();
    int bq = tid & 127, seg = tid >> 7;          // seg 0..7
    const float* zp = zin + bq;
    int kb = seg * 64;
    float acc0 = 0.f, acc1 = 0.f;
#pragma unroll 8
    for (int kk = 0; kk < 64; ++kk) {
        float zv = zp[(size_t)(kb + kk) * B_];
        acc0 = fmaf(Wr[kb + kk], zv, acc0);
        acc1 = fmaf(Wr[K_ + kb + kk], zv, acc1);
    }
    red[seg][0][bq] = acc0;
    red[seg][1][bq] = acc1;
    __syncthreads();
    if (tid < 256) {
        int row = tid >> 7, b = tid & 127;
        float s = 0.f;
#pragma unroll
        for (int t = 0; t < 8; ++t) s += red[t][row][b];
        int o = (l0 + row) * B_ + b;
        zout[o] = fmaf(c, s, d * addv[o]);
    }
}

// ---------------- k_outs: y[b,g] = cvec[b] + sum_{k in row g} zf[k][b] -----
__global__ __launch_bounds__(256) void k_outs(const float* __restrict__ zf,
        const int* __restrict__ rcnt, const int* __restrict__ rell,
        const float* __restrict__ cvec, float* __restrict__ y) {
    __shared__ float sy[128][33];
    int g0 = blockIdx.x * 32;
    int tid = threadIdx.x;
    int gl = tid & 31, bt = tid >> 5;     // 32 genes x 8 b-groups (16 b each)
    int g = g0 + gl;
    int n = rcnt[g];
    const int* rl = rell + g * RW;
    float4 a0 = {0,0,0,0}, a1 = {0,0,0,0}, a2 = {0,0,0,0}, a3 = {0,0,0,0};
    int j = 0;
    for (; j + 2 <= n; j += 2) {
        int k0 = rl[j], k1 = rl[j + 1];
        const float4* z0 = (const float4*)&zf[(size_t)k0 * B_ + bt * 16];
        const float4* z1 = (const float4*)&zf[(size_t)k1 * B_ + bt * 16];
        float4 p0 = z0[0], p1 = z0[1], p2 = z0[2], p3 = z0[3];
        float4 q0 = z1[0], q1 = z1[1], q2 = z1[2], q3 = z1[3];
        a0.x += p0.x + q0.x; a0.y += p0.y + q0.y; a0.z += p0.z + q0.z; a0.w += p0.w + q0.w;
        a1.x += p1.x + q1.x; a1.y += p1.y + q1.y; a1.z += p1.z + q1.z; a1.w += p1.w + q1.w;
        a2.x += p2.x + q2.x; a2.y += p2.y + q2.y; a2.z += p2.z + q2.z; a2.w += p2.w + q2.w;
        a3.x += p3.x + q3.x; a3.y += p3.y + q3.y; a3.z += p3.z + q3.z; a3.w += p3.w + q3.w;
    }
    if (j < n) {
        int k0 = rl[j];
        const float4* z0 = (const float4*)&zf[(size_t)k0 * B_ + bt * 16];
        float4 p0 = z0[0], p1 = z0[1], p2 = z0[2], p3 = z0[3];
        a0.x += p0.x; a0.y += p0.y; a0.z += p0.z; a0.w += p0.w;
        a1.x += p1.x; a1.y += p1.y; a1.z += p1.z; a1.w += p1.w;
        a2.x += p2.x; a2.y += p2.y; a2.z += p2.z; a2.w += p2.w;
        a3.x += p3.x; a3.y += p3.y; a3.z += p3.z; a3.w += p3.w;
    }
    int bb = bt * 16;
    sy[bb +  0][gl] = a0.x; sy[bb +  1][gl] = a0.y; sy[bb +  2][gl] = a0.z; sy[bb +  3][gl] = a0.w;
    sy[bb +  4][gl] = a1.x; sy[bb +  5][gl] = a1.y; sy[bb +  6][gl] = a1.z; sy[bb +  7][gl] = a1.w;
    sy[bb +  8][gl] = a2.x; sy[bb +  9][gl] = a2.y; sy[bb + 10][gl] = a2.z; sy[bb + 11][gl] = a2.w;
    sy[bb + 12][gl] = a3.x; sy[bb + 13][gl] = a3.y; sy[bb + 14][gl] = a3.z; sy[bb + 15][gl] = a3.w;
    __syncthreads();
    int rb = tid >> 1, half = tid & 1;
    float cv = cvec[rb];
    int cb = half * 16;
    float4 o0, o1, o2, o3;
    o0.x = sy[rb][cb + 0] + cv; o0.y = sy[rb][cb + 1] + cv; o0.z = sy[rb][cb + 2] + cv; o0.w = sy[rb][cb + 3] + cv;
    o1.x = sy[rb][cb + 4] + cv; o1.y = sy[rb][cb + 5] + cv; o1.z = sy[rb][cb + 6] + cv; o1.w = sy[rb][cb + 7] + cv;
    o2.x = sy[rb][cb + 8] + cv; o2.y = sy[rb][cb + 9] + cv; o2.z = sy[rb][cb +10] + cv; o2.w = sy[rb][cb +11] + cv;
    o3.x = sy[rb][cb +12] + cv; o3.y = sy[rb][cb +13] + cv; o3.z = sy[rb][cb +14] + cv; o3.w = sy[rb][cb +15] + cv;
    float* yp = &y[(size_t)rb * G_ + g0 + cb];
    *(float4*)&yp[0]  = o0;
    *(float4*)&yp[4]  = o1;
    *(float4*)&yp[8]  = o2;
    *(float4*)&yp[12] = o3;
}

// ---------------------------------------------------------------------------
extern "C" void kernel_launch(void* const* d_in, const int* in_sizes, int n_in,
                              void* d_out, int out_size, void* d_ws, size_t ws_size,
                              hipStream_t stream) {
    const float* ctl   = (const float*)d_in[0];
    const float* dt    = (const float*)d_in[1];
    const int*   cidx  = (const int*)d_in[2];
    // d_in[3] = drug_fp (unused)
    const float* M     = (const float*)d_in[4];
    const float* A     = (const float*)d_in[5];
    const float* W_in  = (const float*)d_in[6];
    const float* b_in  = (const float*)d_in[7];
    const float* cemb  = (const float*)d_in[8];
    const float* W_out = (const float*)d_in[9];
    const float* b_out = (const float*)d_in[10];
    float* y = (float*)d_out;

    char* ws = (char*)d_ws;
    size_t o = 0;
    auto take = [&](size_t bytes) { char* p = ws + o; o = (o + bytes + 255) & ~(size_t)255; return p; };
    float2* xT       = (float2*)take((size_t)G_ * B_ * 8);          // 12.3 MB
    int*    ccnt     = (int*)   take((size_t)CCH * K_ * 4);
    int*    cell_ell = (int*)   take((size_t)CCH * K_ * CW * 4);    // 3.9 MB
    int*    rcnt     = (int*)   take((size_t)G_ * 4);
    int*    rell     = (int*)   take((size_t)G_ * RW * 4);          // 1.5 MB
    float*  cvec     = (float*) take(B_ * 4);
    float*  AT       = (float*) take((size_t)K_ * K_ * 4);          // 1 MB each
    float*  U2       = (float*) take((size_t)K_ * K_ * 4);
    float*  M2       = (float*) take((size_t)K_ * K_ * 4);
    float*  Yop      = (float*) take((size_t)K_ * K_ * 4);
    float*  M4       = (float*) take((size_t)K_ * K_ * 4);
    float*  U4       = (float*) take((size_t)K_ * K_ * 4);
    float*  M8       = (float*) take((size_t)K_ * K_ * 4);
    float*  U8       = (float*) take((size_t)K_ * K_ * 4);
    float*  Wfin     = (float*) take((size_t)K_ * K_ * 4);
    float2* pacc     = (float2*)take((size_t)QSP * K_ * B_ * 8);    // 4 MB
    int*    pdeg     = (int*)   take((size_t)QSP * K_ * 4);
    float*  sout     = (float*) take((size_t)K_ * B_ * 4);
    float*  z10      = (float*) take((size_t)K_ * B_ * 4);
    (void)ws_size; (void)in_sizes; (void)n_in; (void)out_size;

    // transpose + pack inputs
    k_trans<<<dim3(G_ / 32, B_ / 32), dim3(32, 8), 0, stream>>>(ctl, dt, xT);
    // ONE M pass: column-ELL + row-ELL + cvec
    k_msetup<<<CCH + 1, 512, 0, stream>>>(M, ccnt, cell_ell, rcnt, rell,
                                          cidx, cemb, W_out, b_out, cvec);
    // A-side: W_fin = M8*(M2+U2) + U8 via affine doubling (T = 0.9*AT, c=0.1)
    k_at<<<dim3(K_ / 32, K_ / 32), dim3(32, 8), 0, stream>>>(A, AT, U2);
    // M2 = 0.81*AT*AT ; Yop = M2 + U2
    k_mmg<<<dim3(16, 16), 256, 0, stream>>>(AT, AT, nullptr, U2, 0.81f, 0.0f, M2, Yop);
    // M4 = M2*M2 ; U4 = M2*U2 + U2
    k_mmp<<<dim3(16, 16, 2), 256, 0, stream>>>(M2, M2, nullptr, 0.0f, M4,
                                               M2, U2, U2, 1.0f, U4);
    // M8 = M4*M4 ; U8 = M4*U4 + U4
    k_mmp<<<dim3(16, 16, 2), 256, 0, stream>>>(M4, M4, nullptr, 0.0f, M8,
                                               M4, U4, U4, 1.0f, U8);
    // Wfin = M8*Yop + U8
    k_mmg<<<dim3(16, 16), 256, 0, stream>>>(M8, Yop, U8, nullptr, 1.0f, 1.0f, Wfin, nullptr);
    // sparse module aggregation (8-way split) + combine/MLP -> s [K][B]
    k_gather<<<dim3(K_, QSP), 128, 0, stream>>>(ccnt, (const int4*)cell_ell, xT, pacc, pdeg);
    k_smlp<<<(K_ * B_) / 256, 256, 0, stream>>>(pacc, pdeg, W_in, b_in, W_out, sout);
    // one panel: z10 = Wfin * s
    k_panel<<<K_ / 2, 1024, 0, stream>>>(Wfin, sout, sout, 1.0f, 0.0f, z10);
    // sparse output: y[b,g] = cvec[b] + sum_{k in row g} z10[k][b]
    k_outs<<<G_ / 32, 256, 0, stream>>>(z10, rcnt, rell, cvec, y);
}

// Round 6
// 160.243 us; speedup vs baseline: 1.1183x; 1.1183x over previous
//
#include <hip/hip_runtime.h>

// Problem constants (match reference)
#define B_    128
#define G_    12000
#define K_    512
#define H_    64

#define CCH   160      // column chunks
#define CROWS 75       // rows per chunk (160*75 = 12000)
#define CW    12       // max nnz per (column, chunk)  Poisson(1.5): P(>12)~2e-9
#define RW    32       // max nnz per row              Poisson(10.24): P(>32)~5e-9
#define QSP   8        // gather k-split
#define QCH   (CCH / QSP)   // 20 chunks per split

// ---------------- mm body: O = alpha*Aop*Bop + beta*Cop; opt O2 = O + Dop ---
// 32x32 out tile at (k0,l0), BK=64, 256 threads, 2x2 micro. sm: 4480 floats.
__device__ __forceinline__ void mm_body(int k0, int l0, float* __restrict__ sm,
        const float* __restrict__ Aop, const float* __restrict__ Bop,
        const float* __restrict__ Cop, const float* __restrict__ Dop,
        float alpha, float beta, float* __restrict__ O, float* __restrict__ O2) {
    float (*Xa)[68] = (float(*)[68])sm;              // 32*68 = 2176 floats
    float (*Xb)[36] = (float(*)[36])(sm + 2176);     // 64*36 = 2304 floats
    int tid = threadIdx.x;
    int kg = tid & 15, lg = tid >> 4;
    float acc[2][2] = {};
    for (int jj = 0; jj < K_; jj += 64) {
#pragma unroll
        for (int i = 0; i < 2; ++i) {
            int lin = tid + i * 256;
            int r = lin >> 4, c4 = lin & 15;
            *(float4*)&Xa[r][c4 * 4] =
                *(const float4*)&Aop[(size_t)(l0 + r) * K_ + jj + c4 * 4];
        }
#pragma unroll
        for (int i = 0; i < 2; ++i) {
            int lin = tid + i * 256;
            int r = lin >> 3, c4 = lin & 7;
            *(float4*)&Xb[r][c4 * 4] =
                *(const float4*)&Bop[(size_t)(jj + r) * K_ + k0 + c4 * 4];
        }
        __syncthreads();
#pragma unroll 8
        for (int j = 0; j < 64; ++j) {
            float xa0 = Xa[lg * 2][j], xa1 = Xa[lg * 2 + 1][j];
            float xb0 = Xb[j][kg * 2], xb1 = Xb[j][kg * 2 + 1];
            acc[0][0] = fmaf(xa0, xb0, acc[0][0]);
            acc[0][1] = fmaf(xa0, xb1, acc[0][1]);
            acc[1][0] = fmaf(xa1, xb0, acc[1][0]);
            acc[1][1] = fmaf(xa1, xb1, acc[1][1]);
        }
        __syncthreads();
    }
#pragma unroll
    for (int i = 0; i < 2; ++i) {
        size_t idx = (size_t)(l0 + lg * 2 + i) * K_ + k0 + kg * 2;
        float2 v;
        v.x = alpha * acc[i][0];
        v.y = alpha * acc[i][1];
        if (beta != 0.0f) {
            float2 cc = *(const float2*)&Cop[idx];
            v.x = fmaf(beta, cc.x, v.x);
            v.y = fmaf(beta, cc.y, v.y);
        }
        *(float2*)&O[idx] = v;
        if (O2) {
            float2 dd = *(const float2*)&Dop[idx];
            float2 w2; w2.x = v.x + dd.x; w2.y = v.y + dd.y;
            *(float2*)&O2[idx] = w2;
        }
    }
}

// ========== L1: k_pre = {xT pack-transpose | M->MT | AT,U2 | cvec} ==========
__global__ __launch_bounds__(256) void k_pre(
        const float* __restrict__ ctl, const float* __restrict__ dt,
        const float* __restrict__ A, const int* __restrict__ cidx,
        const float* __restrict__ cemb, const float* __restrict__ W_out,
        const float* __restrict__ b_out, const float* __restrict__ M,
        float2* __restrict__ xT, float* __restrict__ MT,
        float* __restrict__ AT, float* __restrict__ U2,
        float* __restrict__ cvec) {
    __shared__ __align__(16) float sm[2 * 32 * 33];
    int bid = blockIdx.x, tid = threadIdx.x;
    int tx = tid & 31, ty = tid >> 5;                 // 32 x 8
    if (bid < 1500) {                                  // xT: [B,G]x2 -> [G][B] float2
        float (*tc)[33] = (float(*)[33])sm;
        float (*td)[33] = (float(*)[33])(sm + 32 * 33);
        int g0 = (bid % 375) * 32, b0 = (bid / 375) * 32;
#pragma unroll
        for (int j = 0; j < 4; ++j) {
            tc[ty + 8 * j][tx] = ctl[(size_t)(b0 + ty + 8 * j) * G_ + g0 + tx];
            td[ty + 8 * j][tx] = dt [(size_t)(b0 + ty + 8 * j) * G_ + g0 + tx];
        }
        __syncthreads();
#pragma unroll
        for (int j = 0; j < 4; ++j)
            xT[(size_t)(g0 + ty + 8 * j) * B_ + b0 + tx] =
                make_float2(tc[tx][ty + 8 * j], td[tx][ty + 8 * j]);
    } else if (bid < 7500) {                           // MT[k][g] = M[g][k]
        int id = bid - 1500;
        float (*t)[33] = (float(*)[33])sm;
        int g0 = (id % 375) * 32, k0 = (id / 375) * 32;
#pragma unroll
        for (int j = 0; j < 4; ++j)
            t[ty + 8 * j][tx] = M[(size_t)(g0 + ty + 8 * j) * K_ + k0 + tx];
        __syncthreads();
#pragma unroll
        for (int j = 0; j < 4; ++j)
            MT[(size_t)(k0 + ty + 8 * j) * G_ + g0 + tx] = t[tx][ty + 8 * j];
    } else if (bid < 7756) {                           // AT + U2 = 0.09*AT + 0.1*I
        int id = bid - 7500;
        float (*t)[33] = (float(*)[33])sm;
        int x0 = (id & 15) * 32, y0 = (id >> 4) * 32;
#pragma unroll
        for (int j = 0; j < 4; ++j)
            t[ty + 8 * j][tx] = A[(size_t)(y0 + ty + 8 * j) * K_ + x0 + tx];
        __syncthreads();
#pragma unroll
        for (int j = 0; j < 4; ++j) {
            int row = x0 + ty + 8 * j, col = y0 + tx;
            float v = t[tx][ty + 8 * j];
            AT[(size_t)row * K_ + col] = v;
            U2[(size_t)row * K_ + col] = 0.09f * v + (row == col ? 0.1f : 0.0f);
        }
    } else {                                           // cvec
        if (tid < B_) {
            int ci = cidx[tid];
            float acc = b_out[0];
#pragma unroll 8
            for (int h = 0; h < H_; ++h)
                acc = fmaf(cemb[ci * H_ + h], W_out[h], acc);
            cvec[tid] = acc;
        }
    }
}

// ========== L2: k_lists = {column-ELL (ballot on MT) | row-ELL | mm P1} =====
__global__ __launch_bounds__(256) void k_lists(
        const float* __restrict__ MT, const float* __restrict__ M,
        int* __restrict__ ccnt, int* __restrict__ cell_ell,
        int* __restrict__ rcnt, int* __restrict__ rell,
        const float* __restrict__ AT, const float* __restrict__ U2,
        float* __restrict__ M2, float* __restrict__ Yop) {
    __shared__ __align__(16) float sm[4480];
    int bid = blockIdx.x, tid = threadIdx.x;
    int w = tid >> 6, lane = tid & 63;
    if (bid < 20480) {                 // column-ELL: one wave per (k, chunk)
        int k = bid & 511;
        int c = ((bid >> 9) << 2) + w;                 // 0..159
        const float* p = MT + (size_t)k * G_ + c * CROWS;
        int* el = cell_ell + ((size_t)c * K_ + k) * CW;
        float v0 = p[lane];                            // genes 0..63 of chunk
        unsigned long long m0 = __ballot(v0 != 0.0f);
        int n0 = __popcll(m0);
        float v1 = (lane < CROWS - 64) ? p[64 + lane] : 0.0f;  // genes 64..74
        unsigned long long m1 = __ballot(v1 != 0.0f);
        if (v0 != 0.0f) {
            int off = __popcll(m0 & ((1ull << lane) - 1ull));
            if (off < CW) el[off] = c * CROWS + lane;
        }
        if (v1 != 0.0f) {
            int off = n0 + __popcll(m1 & ((1ull << lane) - 1ull));
            if (off < CW) el[off] = c * CROWS + 64 + lane;
        }
        if (lane == 0) {
            int cnt = n0 + __popcll(m1);
            ccnt[c * K_ + k] = (cnt <= CW) ? cnt : CW;
        }
    } else if (bid < 23480) {          // row-ELL: one wave per gene row
        int g = (bid - 20480) * 4 + w;
        const float* Mp = M + (size_t)g * K_;
        int base = 0, outb = g * RW;
#pragma unroll
        for (int c0 = 0; c0 < K_; c0 += 64) {
            float v = Mp[c0 + lane];
            unsigned long long mask = __ballot(v != 0.0f);
            int before = __popcll(mask & ((1ull << lane) - 1ull));
            if (v != 0.0f) {
                int o = base + before;
                if (o < RW) rell[outb + o] = c0 + lane;
            }
            base += __popcll(mask);
        }
        if (lane == 0) rcnt[g] = (base <= RW) ? base : RW;
    } else {                           // P1: M2 = 0.81*AT*AT ; Yop = M2 + U2
        int id = bid - 23480;
        mm_body((id & 15) * 32, (id >> 4) * 32, sm,
                AT, AT, nullptr, U2, 0.81f, 0.0f, M2, Yop);
    }
}

// ========== L3: k_gq = {gather (8-way split) | mm P2: M4, U4} ===============
__global__ __launch_bounds__(256) void k_gq(
        const int* __restrict__ ccnt, const int4* __restrict__ cell_ell4,
        const float2* __restrict__ xT,
        float2* __restrict__ pacc, int* __restrict__ pdeg,
        const float* __restrict__ M2, const float* __restrict__ U2,
        float* __restrict__ M4, float* __restrict__ U4) {
    __shared__ __align__(16) float sm[4480];
    int bid = blockIdx.x, tid = threadIdx.x;
    if (bid < 2048) {                  // gather: block = (k, 2 q-slices)
        int k = bid >> 2;
        int q = ((bid & 3) << 1) + (tid >> 7);
        int bq = tid & 127;
        int c0 = q * QCH, c1 = c0 + QCH;
        float a0 = 0.f, a1 = 0.f;
        int deg = 0;
        int n_nxt = ccnt[c0 * K_ + k];
        size_t base = ((size_t)c0 * K_ + k) * 3;
        int4 La = cell_ell4[base], Lb = cell_ell4[base + 1], Lc = cell_ell4[base + 2];
        for (int c = c0; c < c1; ++c) {
            int n = n_nxt;
            int idx[12] = {La.x, La.y, La.z, La.w, Lb.x, Lb.y, Lb.z, Lb.w,
                           Lc.x, Lc.y, Lc.z, Lc.w};
            if (c + 1 < c1) {          // prefetch next chunk's list
                n_nxt = ccnt[(c + 1) * K_ + k];
                size_t nb = ((size_t)(c + 1) * K_ + k) * 3;
                La = cell_ell4[nb]; Lb = cell_ell4[nb + 1]; Lc = cell_ell4[nb + 2];
            }
            deg += n;
#pragma unroll
            for (int j = 0; j < CW; ++j) {
                if (j < n) {           // n is wave-uniform
                    float2 v = xT[(size_t)idx[j] * B_ + bq];
                    a0 += v.x; a1 += v.y;
                }
            }
        }
        pacc[((size_t)q * K_ + k) * B_ + bq] = make_float2(a0, a1);
        if (bq == 0) pdeg[q * K_ + k] = deg;
    } else {                           // P2: M4 = M2*M2 ; U4 = M2*U2 + U2
        int id = bid - 2048;
        int t = id & 255;
        int k0 = (t & 15) * 32, l0 = (t >> 4) * 32;
        if (id < 256)
            mm_body(k0, l0, sm, M2, M2, nullptr, nullptr, 1.0f, 0.0f, M4, nullptr);
        else
            mm_body(k0, l0, sm, M2, U2, U2, nullptr, 1.0f, 1.0f, U4, nullptr);
    }
}

// ========== L4: k_sv = {smlp | mm: V2 = M4*Yop + U4} ========================
__global__ __launch_bounds__(256) void k_sv(
        const float2* __restrict__ pacc, const int* __restrict__ pdeg,
        const float* __restrict__ W_in, const float* __restrict__ b_in,
        const float* __restrict__ W_out, float* __restrict__ sout,
        const float* __restrict__ M4, const float* __restrict__ Yop,
        const float* __restrict__ U4, float* __restrict__ V2) {
    __shared__ __align__(16) float sm[4480];
    int bid = blockIdx.x, tid = threadIdx.x;
    if (bid < 256) {                   // combine partials + fused MLP
        int idx = bid * 256 + tid;     // 65536 = K*B
        int k = idx >> 7, bq = idx & 127;
        float a0 = 0.f, a1 = 0.f;
        int deg = 0;
#pragma unroll
        for (int q = 0; q < QSP; ++q) {
            float2 v = pacc[((size_t)q * K_ + k) * B_ + bq];
            a0 += v.x; a1 += v.y;
            deg += pdeg[q * K_ + k];
        }
        float inv = 1.0f / fmaxf((float)deg, 1.0f);
        float x0 = a0 * inv, x1 = a1 * inv;
        float s = 0.f;
#pragma unroll 8
        for (int h = 0; h < H_; ++h) {
            float v = fmaf(x0, W_in[h], fmaf(x1, W_in[H_ + h], b_in[h]));
            v = fmaxf(v, 0.f);
            s = fmaf(v, W_out[h], s);
        }
        sout[k * B_ + bq] = s;
    } else {
        int id = bid - 256;
        mm_body((id & 15) * 32, (id >> 4) * 32, sm,
                M4, Yop, U4, nullptr, 1.0f, 1.0f, V2, nullptr);
    }
}

// ========== L5: Wfin = M4*V2 + U4 ===========================================
__global__ __launch_bounds__(256) void k_wfin(const float* __restrict__ M4,
        const float* __restrict__ V2, const float* __restrict__ U4,
        float* __restrict__ Wfin) {
    __shared__ __align__(16) float sm[4480];
    mm_body((blockIdx.x & 15) * 32, (blockIdx.x >> 4) * 32, sm,
            M4, V2, U4, nullptr, 1.0f, 1.0f, Wfin, nullptr);
}

// ========== L6: k_panel: z10 = Wfin * s   ([K][B]) ==========================
__global__ __launch_bounds__(1024) void k_panel(const float* __restrict__ W,
        const float* __restrict__ zin, float* __restrict__ zout) {
    __shared__ __align__(16) float Wr[2 * K_];
    __shared__ float red[8][2][128];
    int tid = threadIdx.x;
    int l0 = blockIdx.x * 2;
    if (tid < 256)
        ((float4*)Wr)[tid] = ((const float4*)&W[(size_t)l0 * K_])[tid];
    __syncthreads();
    int bq = tid & 127, seg = tid >> 7;
    const float* zp = zin + bq;
    int kb = seg * 64;
    float acc0 = 0.f, acc1 = 0.f;
#pragma unroll 8
    for (int kk = 0; kk < 64; ++kk) {
        float zv = zp[(size_t)(kb + kk) * B_];
        acc0 = fmaf(Wr[kb + kk], zv, acc0);
        acc1 = fmaf(Wr[K_ + kb + kk], zv, acc1);
    }
    red[seg][0][bq] = acc0;
    red[seg][1][bq] = acc1;
    __syncthreads();
    if (tid < 256) {
        int row = tid >> 7, b = tid & 127;
        float s = 0.f;
#pragma unroll
        for (int t = 0; t < 8; ++t) s += red[t][row][b];
        zout[(l0 + row) * B_ + b] = s;
    }
}

// ========== L7: k_outs: y[b,g] = cvec[b] + sum_{k in row g} zf[k][b] ========
__global__ __launch_bounds__(256) void k_outs(const float* __restrict__ zf,
        const int* __restrict__ rcnt, const int* __restrict__ rell,
        const float* __restrict__ cvec, float* __restrict__ y) {
    __shared__ float sy[128][33];
    int g0 = blockIdx.x * 32;
    int tid = threadIdx.x;
    int gl = tid & 31, bt = tid >> 5;
    int g = g0 + gl;
    int n = rcnt[g];
    const int* rl = rell + g * RW;
    float4 a0 = {0,0,0,0}, a1 = {0,0,0,0}, a2 = {0,0,0,0}, a3 = {0,0,0,0};
    int j = 0;
    for (; j + 2 <= n; j += 2) {
        int k0 = rl[j], k1 = rl[j + 1];
        const float4* z0 = (const float4*)&zf[(size_t)k0 * B_ + bt * 16];
        const float4* z1 = (const float4*)&zf[(size_t)k1 * B_ + bt * 16];
        float4 p0 = z0[0], p1 = z0[1], p2 = z0[2], p3 = z0[3];
        float4 q0 = z1[0], q1 = z1[1], q2 = z1[2], q3 = z1[3];
        a0.x += p0.x + q0.x; a0.y += p0.y + q0.y; a0.z += p0.z + q0.z; a0.w += p0.w + q0.w;
        a1.x += p1.x + q1.x; a1.y += p1.y + q1.y; a1.z += p1.z + q1.z; a1.w += p1.w + q1.w;
        a2.x += p2.x + q2.x; a2.y += p2.y + q2.y; a2.z += p2.z + q2.z; a2.w += p2.w + q2.w;
        a3.x += p3.x + q3.x; a3.y += p3.y + q3.y; a3.z += p3.z + q3.z; a3.w += p3.w + q3.w;
    }
    if (j < n) {
        int k0 = rl[j];
        const float4* z0 = (const float4*)&zf[(size_t)k0 * B_ + bt * 16];
        float4 p0 = z0[0], p1 = z0[1], p2 = z0[2], p3 = z0[3];
        a0.x += p0.x; a0.y += p0.y; a0.z += p0.z; a0.w += p0.w;
        a1.x += p1.x; a1.y += p1.y; a1.z += p1.z; a1.w += p1.w;
        a2.x += p2.x; a2.y += p2.y; a2.z += p2.z; a2.w += p2.w;
        a3.x += p3.x; a3.y += p3.y; a3.z += p3.z; a3.w += p3.w;
    }
    int bb = bt * 16;
    sy[bb +  0][gl] = a0.x; sy[bb +  1][gl] = a0.y; sy[bb +  2][gl] = a0.z; sy[bb +  3][gl] = a0.w;
    sy[bb +  4][gl] = a1.x; sy[bb +  5][gl] = a1.y; sy[bb +  6][gl] = a1.z; sy[bb +  7][gl] = a1.w;
    sy[bb +  8][gl] = a2.x; sy[bb +  9][gl] = a2.y; sy[bb + 10][gl] = a2.z; sy[bb + 11][gl] = a2.w;
    sy[bb + 12][gl] = a3.x; sy[bb + 13][gl] = a3.y; sy[bb + 14][gl] = a3.z; sy[bb + 15][gl] = a3.w;
    __syncthreads();
    int rb = tid >> 1, half = tid & 1;
    float cv = cvec[rb];
    int cb = half * 16;
    float4 o0, o1, o2, o3;
    o0.x = sy[rb][cb + 0] + cv; o0.y = sy[rb][cb + 1] + cv; o0.z = sy[rb][cb + 2] + cv; o0.w = sy[rb][cb + 3] + cv;
    o1.x = sy[rb][cb + 4] + cv; o1.y = sy[rb][cb + 5] + cv; o1.z = sy[rb][cb + 6] + cv; o1.w = sy[rb][cb + 7] + cv;
    o2.x = sy[rb][cb + 8] + cv; o2.y = sy[rb][cb + 9] + cv; o2.z = sy[rb][cb +10] + cv; o2.w = sy[rb][cb +11] + cv;
    o3.x = sy[rb][cb +12] + cv; o3.y = sy[rb][cb +13] + cv; o3.z = sy[rb][cb +14] + cv; o3.w = sy[rb][cb +15] + cv;
    float* yp = &y[(size_t)rb * G_ + g0 + cb];
    *(float4*)&yp[0]  = o0;
    *(float4*)&yp[4]  = o1;
    *(float4*)&yp[8]  = o2;
    *(float4*)&yp[12] = o3;
}

// ---------------------------------------------------------------------------
extern "C" void kernel_launch(void* const* d_in, const int* in_sizes, int n_in,
                              void* d_out, int out_size, void* d_ws, size_t ws_size,
                              hipStream_t stream) {
    const float* ctl   = (const float*)d_in[0];
    const float* dt    = (const float*)d_in[1];
    const int*   cidx  = (const int*)d_in[2];
    // d_in[3] = drug_fp (unused)
    const float* M     = (const float*)d_in[4];
    const float* A     = (const float*)d_in[5];
    const float* W_in  = (const float*)d_in[6];
    const float* b_in  = (const float*)d_in[7];
    const float* cemb  = (const float*)d_in[8];
    const float* W_out = (const float*)d_in[9];
    const float* b_out = (const float*)d_in[10];
    float* y = (float*)d_out;

    char* ws = (char*)d_ws;
    size_t o = 0;
    auto take = [&](size_t bytes) { char* p = ws + o; o = (o + bytes + 255) & ~(size_t)255; return p; };
    float2* xT       = (float2*)take((size_t)G_ * B_ * 8);          // 12.3 MB
    float*  MT       = (float*) take((size_t)K_ * G_ * 4);          // 24.6 MB
    int*    ccnt     = (int*)   take((size_t)CCH * K_ * 4);
    int*    cell_ell = (int*)   take((size_t)CCH * K_ * CW * 4);    // 3.9 MB
    int*    rcnt     = (int*)   take((size_t)G_ * 4);
    int*    rell     = (int*)   take((size_t)G_ * RW * 4);          // 1.5 MB
    float*  cvec     = (float*) take(B_ * 4);
    float*  AT       = (float*) take((size_t)K_ * K_ * 4);          // 1 MB each
    float*  U2       = (float*) take((size_t)K_ * K_ * 4);
    float*  M2       = (float*) take((size_t)K_ * K_ * 4);
    float*  Yop      = (float*) take((size_t)K_ * K_ * 4);
    float*  M4       = (float*) take((size_t)K_ * K_ * 4);
    float*  U4       = (float*) take((size_t)K_ * K_ * 4);
    float*  V2       = (float*) take((size_t)K_ * K_ * 4);
    float*  Wfin     = (float*) take((size_t)K_ * K_ * 4);
    float2* pacc     = (float2*)take((size_t)QSP * K_ * B_ * 8);    // 4 MB
    int*    pdeg     = (int*)   take((size_t)QSP * K_ * 4);
    float*  sout     = (float*) take((size_t)K_ * B_ * 4);
    float*  z10      = (float*) take((size_t)K_ * B_ * 4);
    (void)ws_size; (void)in_sizes; (void)n_in; (void)out_size;

    // L1: xT pack-transpose + M->MT + AT/U2 + cvec    (7757 blocks)
    k_pre<<<7757, 256, 0, stream>>>(ctl, dt, A, cidx, cemb, W_out, b_out, M,
                                    xT, MT, AT, U2, cvec);
    // L2: column-ELL (ballot on MT) + row-ELL + P1 (M2, Yop)   (23736 blocks)
    k_lists<<<23736, 256, 0, stream>>>(MT, M, ccnt, cell_ell, rcnt, rell,
                                       AT, U2, M2, Yop);
    // L3: gather (8-way) + P2 (M4, U4)   (2560 blocks)
    k_gq<<<2560, 256, 0, stream>>>(ccnt, (const int4*)cell_ell, xT, pacc, pdeg,
                                   M2, U2, M4, U4);
    // L4: smlp -> sout + V2 = M4*Yop + U4   (512 blocks)
    k_sv<<<512, 256, 0, stream>>>(pacc, pdeg, W_in, b_in, W_out, sout,
                                  M4, Yop, U4, V2);
    // L5: Wfin = M4*V2 + U4
    k_wfin<<<256, 256, 0, stream>>>(M4, V2, U4, Wfin);
    // L6: z10 = Wfin * s
    k_panel<<<K_ / 2, 1024, 0, stream>>>(Wfin, sout, z10);
    // L7: y[b,g] = cvec[b] + sum_{k in row g} z10[k][b]
    k_outs<<<G_ / 32, 256, 0, stream>>>(z10, rcnt, rell, cvec, y);
}

// Round 7
// 142.499 us; speedup vs baseline: 1.2575x; 1.1245x over previous
//
#include <hip/hip_runtime.h>

// Problem constants (match reference)
#define B_    128
#define G_    12000
#define GP    12288     // G padded to 12*1024 (pad rows are zero => exact)
#define K_    512
#define H_    64
#define RW    32        // max nnz per gene row  Poisson(10.24): P(>32)~5e-9
#define NSEG  12        // GEMM split-K segments
#define SEGG  1024      // genes per segment
#define BKT   64        // GEMM K-step

typedef __attribute__((ext_vector_type(8))) short bf16x8;
typedef __attribute__((ext_vector_type(4))) float f32x4;

__device__ __forceinline__ unsigned short f2bf(float x) {
    union { float f; unsigned u; } v; v.f = x;
    unsigned r = (v.u + 0x7FFFu + ((v.u >> 16) & 1u)) >> 16;
    return (unsigned short)r;
}
__device__ __forceinline__ float bf2f(unsigned short b) {
    union { float f; unsigned u; } v; v.u = ((unsigned)b) << 16;
    return v.f;
}

// ---------------- mm body: O = alpha*Aop*Bop + beta*Cop; opt O2 = O + Dop ---
// 32x32 out tile at (k0,l0), BK=64, 256 threads, 2x2 micro. sm: 4480 floats.
__device__ __forceinline__ void mm_body(int k0, int l0, float* __restrict__ sm,
        const float* __restrict__ Aop, const float* __restrict__ Bop,
        const float* __restrict__ Cop, const float* __restrict__ Dop,
        float alpha, float beta, float* __restrict__ O, float* __restrict__ O2) {
    float (*Xa)[68] = (float(*)[68])sm;              // 32*68 = 2176 floats
    float (*Xb)[36] = (float(*)[36])(sm + 2176);     // 64*36 = 2304 floats
    int tid = threadIdx.x;
    int kg = tid & 15, lg = tid >> 4;
    float acc[2][2] = {};
    for (int jj = 0; jj < K_; jj += 64) {
#pragma unroll
        for (int i = 0; i < 2; ++i) {
            int lin = tid + i * 256;
            int r = lin >> 4, c4 = lin & 15;
            *(float4*)&Xa[r][c4 * 4] =
                *(const float4*)&Aop[(size_t)(l0 + r) * K_ + jj + c4 * 4];
        }
#pragma unroll
        for (int i = 0; i < 2; ++i) {
            int lin = tid + i * 256;
            int r = lin >> 3, c4 = lin & 7;
            *(float4*)&Xb[r][c4 * 4] =
                *(const float4*)&Bop[(size_t)(jj + r) * K_ + k0 + c4 * 4];
        }
        __syncthreads();
#pragma unroll 8
        for (int j = 0; j < 64; ++j) {
            float xa0 = Xa[lg * 2][j], xa1 = Xa[lg * 2 + 1][j];
            float xb0 = Xb[j][kg * 2], xb1 = Xb[j][kg * 2 + 1];
            acc[0][0] = fmaf(xa0, xb0, acc[0][0]);
            acc[0][1] = fmaf(xa0, xb1, acc[0][1]);
            acc[1][0] = fmaf(xa1, xb0, acc[1][0]);
            acc[1][1] = fmaf(xa1, xb1, acc[1][1]);
        }
        __syncthreads();
    }
#pragma unroll
    for (int i = 0; i < 2; ++i) {
        size_t idx = (size_t)(l0 + lg * 2 + i) * K_ + k0 + kg * 2;
        float2 v;
        v.x = alpha * acc[i][0];
        v.y = alpha * acc[i][1];
        if (beta != 0.0f) {
            float2 cc = *(const float2*)&Cop[idx];
            v.x = fmaf(beta, cc.x, v.x);
            v.y = fmaf(beta, cc.y, v.y);
        }
        *(float2*)&O[idx] = v;
        if (O2) {
            float2 dd = *(const float2*)&Dop[idx];
            float2 w2; w2.x = v.x + dd.x; w2.y = v.y + dd.y;
            *(float2*)&O2[idx] = w2;
        }
    }
}

// ========== L1 k_pre: {XpT bf16 hi/lo pack | MTb pack-transpose | AT,U2 |
//                       row-ELL | cvec} ====================================
__global__ __launch_bounds__(256) void k_pre(
        const float* __restrict__ ctl, const float* __restrict__ dt,
        const float* __restrict__ M, const float* __restrict__ A,
        const int* __restrict__ cidx, const float* __restrict__ cemb,
        const float* __restrict__ W_out, const float* __restrict__ b_out,
        unsigned short* __restrict__ XpT, unsigned short* __restrict__ MTb,
        float* __restrict__ AT, float* __restrict__ U2,
        int* __restrict__ rcnt, int* __restrict__ rell,
        float* __restrict__ cvec) {
    __shared__ float t[32][33];
    int bid = blockIdx.x, tid = threadIdx.x;
    if (bid < 3072) {                          // XpT: rows p (hi) and p+256 (lo)
        int p = bid / 12, chunk = bid % 12;
        int ch = p >> 7, b = p & 127;
        const float* src = (ch ? dt : ctl) + (size_t)b * G_;
        int g = chunk * 1024 + tid * 4;
        float x0 = 0.f, x1 = 0.f, x2 = 0.f, x3 = 0.f;
        if (g + 3 < G_) {
            float4 v = *(const float4*)&src[g];
            x0 = v.x; x1 = v.y; x2 = v.z; x3 = v.w;
        } else {
            if (g + 0 < G_) x0 = src[g + 0];
            if (g + 1 < G_) x1 = src[g + 1];
            if (g + 2 < G_) x2 = src[g + 2];
            if (g + 3 < G_) x3 = src[g + 3];
        }
        unsigned short h0 = f2bf(x0), h1 = f2bf(x1), h2 = f2bf(x2), h3 = f2bf(x3);
        ushort4 hv; hv.x = h0; hv.y = h1; hv.z = h2; hv.w = h3;
        *(ushort4*)&XpT[(size_t)p * GP + g] = hv;
        ushort4 lv;
        lv.x = f2bf(x0 - bf2f(h0)); lv.y = f2bf(x1 - bf2f(h1));
        lv.z = f2bf(x2 - bf2f(h2)); lv.w = f2bf(x3 - bf2f(h3));
        *(ushort4*)&XpT[(size_t)(p + 256) * GP + g] = lv;
    } else if (bid < 9216) {                   // MTb[k][g] = bf16(M[g][k])
        int id = bid - 3072;
        int gt = id % 384, kt = id / 384;
        int g0 = gt * 32, k0 = kt * 32;
        int tx = tid & 31, ty = tid >> 5;
#pragma unroll
        for (int j = 0; j < 4; ++j) {
            int g = g0 + ty + 8 * j;
            t[ty + 8 * j][tx] = (g < G_) ? M[(size_t)g * K_ + k0 + tx] : 0.0f;
        }
        __syncthreads();
#pragma unroll
        for (int j = 0; j < 4; ++j)
            MTb[(size_t)(k0 + ty + 8 * j) * GP + g0 + tx] = f2bf(t[tx][ty + 8 * j]);
    } else if (bid < 9472) {                   // AT + U2 = 0.09*AT + 0.1*I
        int id = bid - 9216;
        int x0 = (id & 15) * 32, y0 = (id >> 4) * 32;
        int tx = tid & 31, ty = tid >> 5;
#pragma unroll
        for (int j = 0; j < 4; ++j)
            t[ty + 8 * j][tx] = A[(size_t)(y0 + ty + 8 * j) * K_ + x0 + tx];
        __syncthreads();
#pragma unroll
        for (int j = 0; j < 4; ++j) {
            int row = x0 + ty + 8 * j, col = y0 + tx;
            float v = t[tx][ty + 8 * j];
            AT[(size_t)row * K_ + col] = v;
            U2[(size_t)row * K_ + col] = 0.09f * v + (row == col ? 0.1f : 0.0f);
        }
    } else if (bid < 12472) {                  // row-ELL via wave ballot
        int w = tid >> 6, lane = tid & 63;
        int g = (bid - 9472) * 4 + w;
        const float* Mp = M + (size_t)g * K_;
        int base = 0, outb = g * RW;
#pragma unroll
        for (int c0 = 0; c0 < K_; c0 += 64) {
            float v = Mp[c0 + lane];
            unsigned long long mask = __ballot(v != 0.0f);
            int before = __popcll(mask & ((1ull << lane) - 1ull));
            if (v != 0.0f) {
                int o = base + before;
                if (o < RW) rell[outb + o] = c0 + lane;
            }
            base += __popcll(mask);
        }
        if (lane == 0) rcnt[g] = (base <= RW) ? base : RW;
    } else {                                   // cvec
        if (tid < B_) {
            int ci = cidx[tid];
            float acc = b_out[0];
#pragma unroll 8
            for (int h = 0; h < H_; ++h)
                acc = fmaf(cemb[ci * H_ + h], W_out[h], acc);
            cvec[tid] = acc;
        }
    }
}

// ========== L2 k_gemm: {Cp[seg] = MTb*XpT^T (MFMA, split-K) | P1 mm} ========
__global__ __launch_bounds__(256) void k_gemm(
        const unsigned short* __restrict__ MTb, const unsigned short* __restrict__ XpT,
        float* __restrict__ Cp,
        const float* __restrict__ AT, const float* __restrict__ U2,
        float* __restrict__ M2, float* __restrict__ Yop) {
    __shared__ __align__(16) char smraw[36864];
    int bid = blockIdx.x, tid = threadIdx.x;
    if (bid < 192) {
        unsigned short (*Al)[72] = (unsigned short(*)[72])smraw;           // 128x72
        unsigned short (*Bl)[72] = (unsigned short(*)[72])(smraw + 18432); // 128x72
        int tile = bid & 15, seg = bid >> 4;
        int m0 = (tile & 3) * 128, n0 = (tile >> 2) * 128;
        size_t gbase = (size_t)seg * SEGG;
        int wid = tid >> 6, lane = tid & 63;
        int wm = (wid >> 1) * 64, wn = (wid & 1) * 64;
        int r16 = lane & 15, kg8 = (lane >> 4) * 8;
        int ld_row = tid >> 3, ld_c8 = (tid & 7) * 8;
        f32x4 acc[4][4] = {};
        for (int kk = 0; kk < SEGG; kk += BKT) {
#pragma unroll
            for (int i = 0; i < 4; ++i) {
                int r = ld_row + 32 * i;
                *(uint4*)&Al[r][ld_c8] =
                    *(const uint4*)&MTb[(size_t)(m0 + r) * GP + gbase + kk + ld_c8];
                *(uint4*)&Bl[r][ld_c8] =
                    *(const uint4*)&XpT[(size_t)(n0 + r) * GP + gbase + kk + ld_c8];
            }
            __syncthreads();
#pragma unroll
            for (int ks = 0; ks < 2; ++ks) {
                bf16x8 af[4], bf[4];
#pragma unroll
                for (int mi = 0; mi < 4; ++mi)
                    af[mi] = *(const bf16x8*)&Al[wm + mi * 16 + r16][ks * 32 + kg8];
#pragma unroll
                for (int ni = 0; ni < 4; ++ni)
                    bf[ni] = *(const bf16x8*)&Bl[wn + ni * 16 + r16][ks * 32 + kg8];
#pragma unroll
                for (int mi = 0; mi < 4; ++mi)
#pragma unroll
                    for (int ni = 0; ni < 4; ++ni)
                        acc[mi][ni] = __builtin_amdgcn_mfma_f32_16x16x32_bf16(
                            af[mi], bf[ni], acc[mi][ni], 0, 0, 0);
            }
            __syncthreads();
        }
        float* C = Cp + (size_t)seg * (K_ * K_);
        int cr = (lane >> 4) * 4, cc = lane & 15;
#pragma unroll
        for (int mi = 0; mi < 4; ++mi)
#pragma unroll
            for (int ni = 0; ni < 4; ++ni) {
                size_t rb = (size_t)(m0 + wm + mi * 16 + cr) * K_
                          + (n0 + wn + ni * 16 + cc);
#pragma unroll
                for (int r = 0; r < 4; ++r)
                    C[rb + (size_t)r * K_] = acc[mi][ni][r];
            }
    } else {                                   // P1: M2 = 0.81*AT*AT; Yop = M2+U2
        int id = bid - 192;
        mm_body((id & 15) * 32, (id >> 4) * 32, (float*)smraw,
                AT, AT, nullptr, U2, 0.81f, 0.0f, M2, Yop);
    }
}

// ========== L3 k_red: {reduce Cp + deg + MLP -> sout | P2: M4, U4} ==========
__global__ __launch_bounds__(256) void k_red(
        const float* __restrict__ Cp, const unsigned short* __restrict__ MTb,
        const float* __restrict__ W_in, const float* __restrict__ b_in,
        const float* __restrict__ W_out, float* __restrict__ sout,
        const float* __restrict__ M2, const float* __restrict__ U2,
        float* __restrict__ M4, float* __restrict__ U4) {
    __shared__ __align__(16) float sm[4480];
    int bid = blockIdx.x, tid = threadIdx.x;
    if (bid < 256) {
        int kloc = tid >> 7, b = tid & 127;
        int k = bid * 2 + kloc;
        // degree = nnz of MTb row k (pad rows are zero)
        int cnt = 0;
        const unsigned short* mrow = MTb + (size_t)k * GP;
        for (int g = b; g < GP; g += 128) cnt += (mrow[g] != 0);
#pragma unroll
        for (int off = 32; off; off >>= 1) cnt += __shfl_down(cnt, off, 64);
        __shared__ int dsum[4];
        __shared__ float degs[2];
        int wv = tid >> 6;
        if ((tid & 63) == 0) dsum[wv] = cnt;
        __syncthreads();
        if (tid < 2) degs[tid] = (float)(dsum[tid * 2] + dsum[tid * 2 + 1]);
        __syncthreads();
        float x0 = 0.f, x1 = 0.f;
        for (int s = 0; s < NSEG; ++s) {
            const float* Cb = Cp + (size_t)s * (K_ * K_) + (size_t)k * K_;
            x0 += Cb[b]       + Cb[256 + b];
            x1 += Cb[128 + b] + Cb[384 + b];
        }
        float inv = 1.0f / fmaxf(degs[kloc], 1.0f);
        x0 *= inv; x1 *= inv;
        float s = 0.f;
#pragma unroll 8
        for (int h = 0; h < H_; ++h) {
            float v = fmaf(x0, W_in[h], fmaf(x1, W_in[H_ + h], b_in[h]));
            v = fmaxf(v, 0.f);
            s = fmaf(v, W_out[h], s);
        }
        sout[k * B_ + b] = s;
    } else {                                   // P2: M4 = M2*M2; U4 = M2*U2+U2
        int id = bid - 256;
        int t = id & 255;
        if (id < 256)
            mm_body((t & 15) * 32, (t >> 4) * 32, sm, M2, M2, nullptr, nullptr,
                    1.0f, 0.0f, M4, nullptr);
        else
            mm_body((t & 15) * 32, (t >> 4) * 32, sm, M2, U2, U2, nullptr,
                    1.0f, 1.0f, U4, nullptr);
    }
}

// ========== L4 k_p3: {P3: M8 = M4*M4, U8 = M4*U4+U4 | panel q = Yop*s} ======
__global__ __launch_bounds__(256) void k_p3(
        const float* __restrict__ M4, const float* __restrict__ U4,
        float* __restrict__ M8, float* __restrict__ U8,
        const float* __restrict__ Yop, const float* __restrict__ sout,
        float* __restrict__ q) {
    __shared__ __align__(16) float sm[4480];
    int bid = blockIdx.x, tid = threadIdx.x;
    if (bid < 512) {
        int t = bid & 255;
        if (bid < 256)
            mm_body((t & 15) * 32, (t >> 4) * 32, sm, M4, M4, nullptr, nullptr,
                    1.0f, 0.0f, M8, nullptr);
        else
            mm_body((t & 15) * 32, (t >> 4) * 32, sm, M4, U4, U4, nullptr,
                    1.0f, 1.0f, U8, nullptr);
    } else {                                   // q[l][b] = sum_k Yop[l][k] s[k][b]
        int l0 = (bid - 512) * 2;
        float* Wr = sm;                        // 2 rows x 512
        ((float4*)Wr)[tid] = ((const float4*)&Yop[(size_t)l0 * K_])[tid];
        __syncthreads();
        int b = tid & 127, rh = tid >> 7;
        const float* wp = Wr + rh * K_;
        float acc = 0.f;
#pragma unroll 8
        for (int k = 0; k < K_; ++k)
            acc = fmaf(wp[k], sout[k * B_ + b], acc);
        q[(l0 + rh) * B_ + b] = acc;
    }
}

// ========== L5 k_zfin: z10 = M8*q + U8*s ====================================
__global__ __launch_bounds__(256) void k_zfin(
        const float* __restrict__ M8, const float* __restrict__ U8,
        const float* __restrict__ q, const float* __restrict__ sout,
        float* __restrict__ z10) {
    __shared__ __align__(16) float Wr[4 * K_];
    int tid = threadIdx.x;
    int l0 = blockIdx.x * 2;
    ((float4*)Wr)[tid]            = ((const float4*)&M8[(size_t)l0 * K_])[tid];
    ((float4*)(Wr + 2 * K_))[tid] = ((const float4*)&U8[(size_t)l0 * K_])[tid];
    __syncthreads();
    int b = tid & 127, rh = tid >> 7;
    const float* mp = Wr + rh * K_;
    const float* up = Wr + 2 * K_ + rh * K_;
    float acc = 0.f;
#pragma unroll 4
    for (int k = 0; k < K_; ++k) {
        acc = fmaf(mp[k], q[k * B_ + b], acc);
        acc = fmaf(up[k], sout[k * B_ + b], acc);
    }
    z10[(l0 + rh) * B_ + b] = acc;
}

// ========== L6 k_outs: y[b,g] = cvec[b] + sum_{k in row g} zf[k][b] =========
__global__ __launch_bounds__(256) void k_outs(const float* __restrict__ zf,
        const int* __restrict__ rcnt, const int* __restrict__ rell,
        const float* __restrict__ cvec, float* __restrict__ y) {
    __shared__ float sy[128][33];
    int g0 = blockIdx.x * 32;
    int tid = threadIdx.x;
    int gl = tid & 31, bt = tid >> 5;
    int g = g0 + gl;
    int n = rcnt[g];
    const int* rl = rell + g * RW;
    float4 a0 = {0,0,0,0}, a1 = {0,0,0,0}, a2 = {0,0,0,0}, a3 = {0,0,0,0};
    int j = 0;
    for (; j + 2 <= n; j += 2) {
        int k0 = rl[j], k1 = rl[j + 1];
        const float4* z0 = (const float4*)&zf[(size_t)k0 * B_ + bt * 16];
        const float4* z1 = (const float4*)&zf[(size_t)k1 * B_ + bt * 16];
        float4 p0 = z0[0], p1 = z0[1], p2 = z0[2], p3 = z0[3];
        float4 q0 = z1[0], q1 = z1[1], q2 = z1[2], q3 = z1[3];
        a0.x += p0.x + q0.x; a0.y += p0.y + q0.y; a0.z += p0.z + q0.z; a0.w += p0.w + q0.w;
        a1.x += p1.x + q1.x; a1.y += p1.y + q1.y; a1.z += p1.z + q1.z; a1.w += p1.w + q1.w;
        a2.x += p2.x + q2.x; a2.y += p2.y + q2.y; a2.z += p2.z + q2.z; a2.w += p2.w + q2.w;
        a3.x += p3.x + q3.x; a3.y += p3.y + q3.y; a3.z += p3.z + q3.z; a3.w += p3.w + q3.w;
    }
    if (j < n) {
        int k0 = rl[j];
        const float4* z0 = (const float4*)&zf[(size_t)k0 * B_ + bt * 16];
        float4 p0 = z0[0], p1 = z0[1], p2 = z0[2], p3 = z0[3];
        a0.x += p0.x; a0.y += p0.y; a0.z += p0.z; a0.w += p0.w;
        a1.x += p1.x; a1.y += p1.y; a1.z += p1.z; a1.w += p1.w;
        a2.x += p2.x; a2.y += p2.y; a2.z += p2.z; a2.w += p2.w;
        a3.x += p3.x; a3.y += p3.y; a3.z += p3.z; a3.w += p3.w;
    }
    int bb = bt * 16;
    sy[bb +  0][gl] = a0.x; sy[bb +  1][gl] = a0.y; sy[bb +  2][gl] = a0.z; sy[bb +  3][gl] = a0.w;
    sy[bb +  4][gl] = a1.x; sy[bb +  5][gl] = a1.y; sy[bb +  6][gl] = a1.z; sy[bb +  7][gl] = a1.w;
    sy[bb +  8][gl] = a2.x; sy[bb +  9][gl] = a2.y; sy[bb + 10][gl] = a2.z; sy[bb + 11][gl] = a2.w;
    sy[bb + 12][gl] = a3.x; sy[bb + 13][gl] = a3.y; sy[bb + 14][gl] = a3.z; sy[bb + 15][gl] = a3.w;
    __syncthreads();
    int rb = tid >> 1, half = tid & 1;
    float cv = cvec[rb];
    int cb = half * 16;
    float4 o0, o1, o2, o3;
    o0.x = sy[rb][cb + 0] + cv; o0.y = sy[rb][cb + 1] + cv; o0.z = sy[rb][cb + 2] + cv; o0.w = sy[rb][cb + 3] + cv;
    o1.x = sy[rb][cb + 4] + cv; o1.y = sy[rb][cb + 5] + cv; o1.z = sy[rb][cb + 6] + cv; o1.w = sy[rb][cb + 7] + cv;
    o2.x = sy[rb][cb + 8] + cv; o2.y = sy[rb][cb + 9] + cv; o2.z = sy[rb][cb +10] + cv; o2.w = sy[rb][cb +11] + cv;
    o3.x = sy[rb][cb +12] + cv; o3.y = sy[rb][cb +13] + cv; o3.z = sy[rb][cb +14] + cv; o3.w = sy[rb][cb +15] + cv;
    float* yp = &y[(size_t)rb * G_ + g0 + cb];
    *(float4*)&yp[0]  = o0;
    *(float4*)&yp[4]  = o1;
    *(float4*)&yp[8]  = o2;
    *(float4*)&yp[12] = o3;
}

// ---------------------------------------------------------------------------
extern "C" void kernel_launch(void* const* d_in, const int* in_sizes, int n_in,
                              void* d_out, int out_size, void* d_ws, size_t ws_size,
                              hipStream_t stream) {
    const float* ctl   = (const float*)d_in[0];
    const float* dt    = (const float*)d_in[1];
    const int*   cidx  = (const int*)d_in[2];
    // d_in[3] = drug_fp (unused)
    const float* M     = (const float*)d_in[4];
    const float* A     = (const float*)d_in[5];
    const float* W_in  = (const float*)d_in[6];
    const float* b_in  = (const float*)d_in[7];
    const float* cemb  = (const float*)d_in[8];
    const float* W_out = (const float*)d_in[9];
    const float* b_out = (const float*)d_in[10];
    float* y = (float*)d_out;

    char* ws = (char*)d_ws;
    size_t o = 0;
    auto take = [&](size_t bytes) { char* p = ws + o; o = (o + bytes + 255) & ~(size_t)255; return p; };
    unsigned short* XpT = (unsigned short*)take((size_t)512 * GP * 2);  // 12.6 MB
    unsigned short* MTb = (unsigned short*)take((size_t)K_ * GP * 2);   // 12.6 MB
    float* Cp   = (float*)take((size_t)NSEG * K_ * K_ * 4);             // 12.6 MB
    int*   rcnt = (int*)  take((size_t)G_ * 4);
    int*   rell = (int*)  take((size_t)G_ * RW * 4);                    // 1.5 MB
    float* cvec = (float*)take(B_ * 4);
    float* AT   = (float*)take((size_t)K_ * K_ * 4);                    // 1 MB each
    float* U2   = (float*)take((size_t)K_ * K_ * 4);
    float* M2   = (float*)take((size_t)K_ * K_ * 4);
    float* Yop  = (float*)take((size_t)K_ * K_ * 4);
    float* M4   = (float*)take((size_t)K_ * K_ * 4);
    float* U4   = (float*)take((size_t)K_ * K_ * 4);
    float* M8   = (float*)take((size_t)K_ * K_ * 4);
    float* U8   = (float*)take((size_t)K_ * K_ * 4);
    float* sout = (float*)take((size_t)K_ * B_ * 4);
    float* q    = (float*)take((size_t)K_ * B_ * 4);
    float* z10  = (float*)take((size_t)K_ * B_ * 4);
    (void)ws_size; (void)in_sizes; (void)n_in; (void)out_size;

    // L1: packs (XpT hi/lo, MTb) + AT/U2 + row-ELL + cvec
    k_pre<<<12473, 256, 0, stream>>>(ctl, dt, M, A, cidx, cemb, W_out, b_out,
                                     XpT, MTb, AT, U2, rcnt, rell, cvec);
    // L2: split-K MFMA GEMM (Cp) + P1 (M2, Yop)
    k_gemm<<<448, 256, 0, stream>>>(MTb, XpT, Cp, AT, U2, M2, Yop);
    // L3: reduce Cp + deg + MLP -> sout ; P2 (M4, U4)
    k_red<<<768, 256, 0, stream>>>(Cp, MTb, W_in, b_in, W_out, sout,
                                   M2, U2, M4, U4);
    // L4: P3 (M8, U8) + panel q = Yop*s
    k_p3<<<768, 256, 0, stream>>>(M4, U4, M8, U8, Yop, sout, q);
    // L5: z10 = M8*q + U8*s
    k_zfin<<<K_ / 2, 256, 0, stream>>>(M8, U8, q, sout, z10);
    // L6: y[b,g] = cvec[b] + sum_{k in row g} z10[k][b]
    k_outs<<<G_ / 32, 256, 0, stream>>>(z10, rcnt, rell, cvec, y);
}

// Round 8
// 118.712 us; speedup vs baseline: 1.5095x; 1.2004x over previous
//
#include <hip/hip_runtime.h>

// Problem constants (match reference)
#define B_    128
#define G_    12000
#define GP    12288     // G padded to 12*1024 (pad rows are zero => exact)
#define K_    512
#define H_    64
#define RW    32        // max nnz per gene row  Poisson(10.24): P(>32)~5e-9
#define NSEG  12        // GEMM split-K segments
#define SEGG  1024      // genes per segment
#define BKT   64        // GEMM K-step

typedef __attribute__((ext_vector_type(8))) short bf16x8;
typedef __attribute__((ext_vector_type(4))) float f32x4;

__device__ __forceinline__ unsigned short f2bf(float x) {
    union { float f; unsigned u; } v; v.f = x;
    unsigned r = (v.u + 0x7FFFu + ((v.u >> 16) & 1u)) >> 16;
    return (unsigned short)r;
}
__device__ __forceinline__ float bf2f(unsigned short b) {
    union { float f; unsigned u; } v; v.u = ((unsigned)b) << 16;
    return v.f;
}

// ---------------- mm body: O = alpha*Aop*Bop + beta*Cop; opt O2 = O + Dop ---
// 32x32 out tile at (k0,l0), BK=64, 256 threads, 2x2 micro. sm: 4480 floats.
__device__ __forceinline__ void mm_body(int k0, int l0, float* __restrict__ sm,
        const float* __restrict__ Aop, const float* __restrict__ Bop,
        const float* __restrict__ Cop, const float* __restrict__ Dop,
        float alpha, float beta, float* __restrict__ O, float* __restrict__ O2) {
    float (*Xa)[68] = (float(*)[68])sm;              // 32*68 = 2176 floats
    float (*Xb)[36] = (float(*)[36])(sm + 2176);     // 64*36 = 2304 floats
    int tid = threadIdx.x;
    int kg = tid & 15, lg = tid >> 4;
    float acc[2][2] = {};
    for (int jj = 0; jj < K_; jj += 64) {
#pragma unroll
        for (int i = 0; i < 2; ++i) {
            int lin = tid + i * 256;
            int r = lin >> 4, c4 = lin & 15;
            *(float4*)&Xa[r][c4 * 4] =
                *(const float4*)&Aop[(size_t)(l0 + r) * K_ + jj + c4 * 4];
        }
#pragma unroll
        for (int i = 0; i < 2; ++i) {
            int lin = tid + i * 256;
            int r = lin >> 3, c4 = lin & 7;
            *(float4*)&Xb[r][c4 * 4] =
                *(const float4*)&Bop[(size_t)(jj + r) * K_ + k0 + c4 * 4];
        }
        __syncthreads();
#pragma unroll 8
        for (int j = 0; j < 64; ++j) {
            float xa0 = Xa[lg * 2][j], xa1 = Xa[lg * 2 + 1][j];
            float xb0 = Xb[j][kg * 2], xb1 = Xb[j][kg * 2 + 1];
            acc[0][0] = fmaf(xa0, xb0, acc[0][0]);
            acc[0][1] = fmaf(xa0, xb1, acc[0][1]);
            acc[1][0] = fmaf(xa1, xb0, acc[1][0]);
            acc[1][1] = fmaf(xa1, xb1, acc[1][1]);
        }
        __syncthreads();
    }
#pragma unroll
    for (int i = 0; i < 2; ++i) {
        size_t idx = (size_t)(l0 + lg * 2 + i) * K_ + k0 + kg * 2;
        float2 v;
        v.x = alpha * acc[i][0];
        v.y = alpha * acc[i][1];
        if (beta != 0.0f) {
            float2 cc = *(const float2*)&Cop[idx];
            v.x = fmaf(beta, cc.x, v.x);
            v.y = fmaf(beta, cc.y, v.y);
        }
        *(float2*)&O[idx] = v;
        if (O2) {
            float2 dd = *(const float2*)&Dop[idx];
            float2 w2; w2.x = v.x + dd.x; w2.y = v.y + dd.y;
            *(float2*)&O2[idx] = w2;
        }
    }
}

// ========== L1 k_pre: {XpT bf16 hi/lo pack | MTb pack-transpose | AT,U2 |
//                       row-ELL | cvec} ====================================
__global__ __launch_bounds__(256) void k_pre(
        const float* __restrict__ ctl, const float* __restrict__ dt,
        const float* __restrict__ M, const float* __restrict__ A,
        const int* __restrict__ cidx, const float* __restrict__ cemb,
        const float* __restrict__ W_out, const float* __restrict__ b_out,
        unsigned short* __restrict__ XpT, unsigned short* __restrict__ MTb,
        float* __restrict__ AT, float* __restrict__ U2,
        int* __restrict__ rcnt, int* __restrict__ rell,
        float* __restrict__ cvec) {
    __shared__ float t[32][33];
    int bid = blockIdx.x, tid = threadIdx.x;
    if (bid < 3072) {                          // XpT: rows p (hi) and p+256 (lo)
        int p = bid / 12, chunk = bid % 12;
        int ch = p >> 7, b = p & 127;
        const float* src = (ch ? dt : ctl) + (size_t)b * G_;
        int g = chunk * 1024 + tid * 4;
        float x0 = 0.f, x1 = 0.f, x2 = 0.f, x3 = 0.f;
        if (g + 3 < G_) {
            float4 v = *(const float4*)&src[g];
            x0 = v.x; x1 = v.y; x2 = v.z; x3 = v.w;
        } else {
            if (g + 0 < G_) x0 = src[g + 0];
            if (g + 1 < G_) x1 = src[g + 1];
            if (g + 2 < G_) x2 = src[g + 2];
            if (g + 3 < G_) x3 = src[g + 3];
        }
        unsigned short h0 = f2bf(x0), h1 = f2bf(x1), h2 = f2bf(x2), h3 = f2bf(x3);
        ushort4 hv; hv.x = h0; hv.y = h1; hv.z = h2; hv.w = h3;
        *(ushort4*)&XpT[(size_t)p * GP + g] = hv;
        ushort4 lv;
        lv.x = f2bf(x0 - bf2f(h0)); lv.y = f2bf(x1 - bf2f(h1));
        lv.z = f2bf(x2 - bf2f(h2)); lv.w = f2bf(x3 - bf2f(h3));
        *(ushort4*)&XpT[(size_t)(p + 256) * GP + g] = lv;
    } else if (bid < 9216) {                   // MTb[k][g] = bf16(M[g][k])
        int id = bid - 3072;
        int gt = id % 384, kt = id / 384;
        int g0 = gt * 32, k0 = kt * 32;
        int tx = tid & 31, ty = tid >> 5;
#pragma unroll
        for (int j = 0; j < 4; ++j) {
            int g = g0 + ty + 8 * j;
            t[ty + 8 * j][tx] = (g < G_) ? M[(size_t)g * K_ + k0 + tx] : 0.0f;
        }
        __syncthreads();
#pragma unroll
        for (int j = 0; j < 4; ++j)
            MTb[(size_t)(k0 + ty + 8 * j) * GP + g0 + tx] = f2bf(t[tx][ty + 8 * j]);
    } else if (bid < 9472) {                   // AT + U2 = 0.09*AT + 0.1*I
        int id = bid - 9216;
        int x0 = (id & 15) * 32, y0 = (id >> 4) * 32;
        int tx = tid & 31, ty = tid >> 5;
#pragma unroll
        for (int j = 0; j < 4; ++j)
            t[ty + 8 * j][tx] = A[(size_t)(y0 + ty + 8 * j) * K_ + x0 + tx];
        __syncthreads();
#pragma unroll
        for (int j = 0; j < 4; ++j) {
            int row = x0 + ty + 8 * j, col = y0 + tx;
            float v = t[tx][ty + 8 * j];
            AT[(size_t)row * K_ + col] = v;
            U2[(size_t)row * K_ + col] = 0.09f * v + (row == col ? 0.1f : 0.0f);
        }
    } else if (bid < 12472) {                  // row-ELL via wave ballot
        int w = tid >> 6, lane = tid & 63;
        int g = (bid - 9472) * 4 + w;
        const float* Mp = M + (size_t)g * K_;
        int base = 0, outb = g * RW;
#pragma unroll
        for (int c0 = 0; c0 < K_; c0 += 64) {
            float v = Mp[c0 + lane];
            unsigned long long mask = __ballot(v != 0.0f);
            int before = __popcll(mask & ((1ull << lane) - 1ull));
            if (v != 0.0f) {
                int o = base + before;
                if (o < RW) rell[outb + o] = c0 + lane;
            }
            base += __popcll(mask);
        }
        if (lane == 0) rcnt[g] = (base <= RW) ? base : RW;
    } else {                                   // cvec
        if (tid < B_) {
            int ci = cidx[tid];
            float acc = b_out[0];
#pragma unroll 8
            for (int h = 0; h < H_; ++h)
                acc = fmaf(cemb[ci * H_ + h], W_out[h], acc);
            cvec[tid] = acc;
        }
    }
}

// ========== L2 k_gemm: {Cp[seg] = MTb*XpT^T (MFMA, split-K) | P1 mm} ========
__global__ __launch_bounds__(256) void k_gemm(
        const unsigned short* __restrict__ MTb, const unsigned short* __restrict__ XpT,
        float* __restrict__ Cp,
        const float* __restrict__ AT, const float* __restrict__ U2,
        float* __restrict__ M2, float* __restrict__ Yop) {
    __shared__ __align__(16) char smraw[36864];
    int bid = blockIdx.x, tid = threadIdx.x;
    if (bid < 192) {
        unsigned short (*Al)[72] = (unsigned short(*)[72])smraw;           // 128x72
        unsigned short (*Bl)[72] = (unsigned short(*)[72])(smraw + 18432); // 128x72
        int tile = bid & 15, seg = bid >> 4;
        int m0 = (tile & 3) * 128, n0 = (tile >> 2) * 128;
        size_t gbase = (size_t)seg * SEGG;
        int wid = tid >> 6, lane = tid & 63;
        int wm = (wid >> 1) * 64, wn = (wid & 1) * 64;
        int r16 = lane & 15, kg8 = (lane >> 4) * 8;
        int ld_row = tid >> 3, ld_c8 = (tid & 7) * 8;
        f32x4 acc[4][4] = {};
        for (int kk = 0; kk < SEGG; kk += BKT) {
#pragma unroll
            for (int i = 0; i < 4; ++i) {
                int r = ld_row + 32 * i;
                *(uint4*)&Al[r][ld_c8] =
                    *(const uint4*)&MTb[(size_t)(m0 + r) * GP + gbase + kk + ld_c8];
                *(uint4*)&Bl[r][ld_c8] =
                    *(const uint4*)&XpT[(size_t)(n0 + r) * GP + gbase + kk + ld_c8];
            }
            __syncthreads();
#pragma unroll
            for (int ks = 0; ks < 2; ++ks) {
                bf16x8 af[4], bf[4];
#pragma unroll
                for (int mi = 0; mi < 4; ++mi)
                    af[mi] = *(const bf16x8*)&Al[wm + mi * 16 + r16][ks * 32 + kg8];
#pragma unroll
                for (int ni = 0; ni < 4; ++ni)
                    bf[ni] = *(const bf16x8*)&Bl[wn + ni * 16 + r16][ks * 32 + kg8];
#pragma unroll
                for (int mi = 0; mi < 4; ++mi)
#pragma unroll
                    for (int ni = 0; ni < 4; ++ni)
                        acc[mi][ni] = __builtin_amdgcn_mfma_f32_16x16x32_bf16(
                            af[mi], bf[ni], acc[mi][ni], 0, 0, 0);
            }
            __syncthreads();
        }
        float* C = Cp + (size_t)seg * (K_ * K_);
        int cr = (lane >> 4) * 4, cc = lane & 15;
#pragma unroll
        for (int mi = 0; mi < 4; ++mi)
#pragma unroll
            for (int ni = 0; ni < 4; ++ni) {
                size_t rb = (size_t)(m0 + wm + mi * 16 + cr) * K_
                          + (n0 + wn + ni * 16 + cc);
#pragma unroll
                for (int r = 0; r < 4; ++r)
                    C[rb + (size_t)r * K_] = acc[mi][ni][r];
            }
    } else {                                   // P1: M2 = 0.81*AT*AT; Yop = M2+U2
        int id = bid - 192;
        mm_body((id & 15) * 32, (id >> 4) * 32, (float*)smraw,
                AT, AT, nullptr, U2, 0.81f, 0.0f, M2, Yop);
    }
}

// ========== L3 k_red: {reduce Cp + deg + MLP -> sout | P2: M4, U4} ==========
__global__ __launch_bounds__(256) void k_red(
        const float* __restrict__ Cp, const unsigned short* __restrict__ MTb,
        const float* __restrict__ W_in, const float* __restrict__ b_in,
        const float* __restrict__ W_out, float* __restrict__ sout,
        const float* __restrict__ M2, const float* __restrict__ U2,
        float* __restrict__ M4, float* __restrict__ U4) {
    __shared__ __align__(16) float sm[4480];
    int bid = blockIdx.x, tid = threadIdx.x;
    if (bid < 256) {
        int kloc = tid >> 7, b = tid & 127;
        int k = bid * 2 + kloc;
        // degree = nnz of MTb row k (pad rows are zero)
        int cnt = 0;
        const unsigned short* mrow = MTb + (size_t)k * GP;
        for (int g = b; g < GP; g += 128) cnt += (mrow[g] != 0);
#pragma unroll
        for (int off = 32; off; off >>= 1) cnt += __shfl_down(cnt, off, 64);
        __shared__ int dsum[4];
        __shared__ float degs[2];
        int wv = tid >> 6;
        if ((tid & 63) == 0) dsum[wv] = cnt;
        __syncthreads();
        if (tid < 2) degs[tid] = (float)(dsum[tid * 2] + dsum[tid * 2 + 1]);
        __syncthreads();
        float x0 = 0.f, x1 = 0.f;
        for (int s = 0; s < NSEG; ++s) {
            const float* Cb = Cp + (size_t)s * (K_ * K_) + (size_t)k * K_;
            x0 += Cb[b]       + Cb[256 + b];
            x1 += Cb[128 + b] + Cb[384 + b];
        }
        float inv = 1.0f / fmaxf(degs[kloc], 1.0f);
        x0 *= inv; x1 *= inv;
        float s = 0.f;
#pragma unroll 8
        for (int h = 0; h < H_; ++h) {
            float v = fmaf(x0, W_in[h], fmaf(x1, W_in[H_ + h], b_in[h]));
            v = fmaxf(v, 0.f);
            s = fmaf(v, W_out[h], s);
        }
        sout[k * B_ + b] = s;
    } else {                                   // P2: M4 = M2*M2; U4 = M2*U2+U2
        int id = bid - 256;
        int t = id & 255;
        if (id < 256)
            mm_body((t & 15) * 32, (t >> 4) * 32, sm, M2, M2, nullptr, nullptr,
                    1.0f, 0.0f, M4, nullptr);
        else
            mm_body((t & 15) * 32, (t >> 4) * 32, sm, M2, U2, U2, nullptr,
                    1.0f, 1.0f, U4, nullptr);
    }
}

// ========== L4 k_p3: {P3: M8 = M4*M4, U8 = M4*U4+U4 | panel q = Yop*s} ======
// panel part restructured: one row per block, 2 k-segments, 4 accumulators,
// LDS reduce — kills the 512-long serial fma chain of round 7.
__global__ __launch_bounds__(256) void k_p3(
        const float* __restrict__ M4, const float* __restrict__ U4,
        float* __restrict__ M8, float* __restrict__ U8,
        const float* __restrict__ Yop, const float* __restrict__ sout,
        float* __restrict__ q) {
    __shared__ __align__(16) float sm[4480];
    int bid = blockIdx.x, tid = threadIdx.x;
    if (bid < 512) {
        int t = bid & 255;
        if (bid < 256)
            mm_body((t & 15) * 32, (t >> 4) * 32, sm, M4, M4, nullptr, nullptr,
                    1.0f, 0.0f, M8, nullptr);
        else
            mm_body((t & 15) * 32, (t >> 4) * 32, sm, M4, U4, U4, nullptr,
                    1.0f, 1.0f, U8, nullptr);
    } else {                                   // q[l][b] = sum_k Yop[l][k] s[k][b]
        int l = bid - 512;                     // 0..511
        float* Wr  = sm;                       // 512 floats
        float* red = sm + 512;                 // 256 floats
        if (tid < 128)
            ((float4*)Wr)[tid] = ((const float4*)&Yop[(size_t)l * K_])[tid];
        __syncthreads();
        int b = tid & 127, seg = tid >> 7;     // 2 segs x 256 k
        int kb = seg * 256;
        float a0 = 0.f, a1 = 0.f, a2 = 0.f, a3 = 0.f;
#pragma unroll 4
        for (int kk = 0; kk < 256; kk += 4) {
            int k = kb + kk;
            a0 = fmaf(Wr[k + 0], sout[(k + 0) * B_ + b], a0);
            a1 = fmaf(Wr[k + 1], sout[(k + 1) * B_ + b], a1);
            a2 = fmaf(Wr[k + 2], sout[(k + 2) * B_ + b], a2);
            a3 = fmaf(Wr[k + 3], sout[(k + 3) * B_ + b], a3);
        }
        red[seg * 128 + b] = (a0 + a1) + (a2 + a3);
        __syncthreads();
        if (tid < 128)
            q[l * B_ + b] = red[b] + red[128 + b];
    }
}

// ========== L5 k_zfin: z10 = M8*q + U8*s  (1024 thr, 8 k-segs, LDS reduce) ==
__global__ __launch_bounds__(1024) void k_zfin(
        const float* __restrict__ M8, const float* __restrict__ U8,
        const float* __restrict__ q, const float* __restrict__ sout,
        float* __restrict__ z10) {
    __shared__ __align__(16) float Wr[4 * K_];   // M8 row0,1 | U8 row0,1
    __shared__ float red[8][2][128];
    int tid = threadIdx.x;
    int l0 = blockIdx.x * 2;
    if (tid < 256)
        ((float4*)Wr)[tid] = ((const float4*)&M8[(size_t)l0 * K_])[tid];
    else if (tid < 512)
        ((float4*)&Wr[2 * K_])[tid - 256] =
            ((const float4*)&U8[(size_t)l0 * K_])[tid - 256];
    __syncthreads();
    int b = tid & 127, seg = tid >> 7;           // 8 segs x 64 k
    int kb = seg * 64;
    float a0m = 0.f, a0u = 0.f, a1m = 0.f, a1u = 0.f;
#pragma unroll 8
    for (int kk = 0; kk < 64; ++kk) {
        int k = kb + kk;
        float qv = q[k * B_ + b];
        float sv = sout[k * B_ + b];
        a0m = fmaf(Wr[k], qv, a0m);
        a0u = fmaf(Wr[2 * K_ + k], sv, a0u);
        a1m = fmaf(Wr[K_ + k], qv, a1m);
        a1u = fmaf(Wr[3 * K_ + k], sv, a1u);
    }
    red[seg][0][b] = a0m + a0u;
    red[seg][1][b] = a1m + a1u;
    __syncthreads();
    if (tid < 256) {
        int row = tid >> 7, bb = tid & 127;
        float t = 0.f;
#pragma unroll
        for (int u = 0; u < 8; ++u) t += red[u][row][bb];
        z10[(l0 + row) * B_ + bb] = t;
    }
}

// ========== L6 k_outs: y[b,g] = cvec[b] + sum_{k in row g} zf[k][b] =========
__global__ __launch_bounds__(256) void k_outs(const float* __restrict__ zf,
        const int* __restrict__ rcnt, const int* __restrict__ rell,
        const float* __restrict__ cvec, float* __restrict__ y) {
    __shared__ float sy[128][33];
    int g0 = blockIdx.x * 32;
    int tid = threadIdx.x;
    int gl = tid & 31, bt = tid >> 5;
    int g = g0 + gl;
    int n = rcnt[g];
    const int* rl = rell + g * RW;
    float4 a0 = {0,0,0,0}, a1 = {0,0,0,0}, a2 = {0,0,0,0}, a3 = {0,0,0,0};
    int j = 0;
    for (; j + 2 <= n; j += 2) {
        int k0 = rl[j], k1 = rl[j + 1];
        const float4* z0 = (const float4*)&zf[(size_t)k0 * B_ + bt * 16];
        const float4* z1 = (const float4*)&zf[(size_t)k1 * B_ + bt * 16];
        float4 p0 = z0[0], p1 = z0[1], p2 = z0[2], p3 = z0[3];
        float4 q0 = z1[0], q1 = z1[1], q2 = z1[2], q3 = z1[3];
        a0.x += p0.x + q0.x; a0.y += p0.y + q0.y; a0.z += p0.z + q0.z; a0.w += p0.w + q0.w;
        a1.x += p1.x + q1.x; a1.y += p1.y + q1.y; a1.z += p1.z + q1.z; a1.w += p1.w + q1.w;
        a2.x += p2.x + q2.x; a2.y += p2.y + q2.y; a2.z += p2.z + q2.z; a2.w += p2.w + q2.w;
        a3.x += p3.x + q3.x; a3.y += p3.y + q3.y; a3.z += p3.z + q3.z; a3.w += p3.w + q3.w;
    }
    if (j < n) {
        int k0 = rl[j];
        const float4* z0 = (const float4*)&zf[(size_t)k0 * B_ + bt * 16];
        float4 p0 = z0[0], p1 = z0[1], p2 = z0[2], p3 = z0[3];
        a0.x += p0.x; a0.y += p0.y; a0.z += p0.z; a0.w += p0.w;
        a1.x += p1.x; a1.y += p1.y; a1.z += p1.z; a1.w += p1.w;
        a2.x += p2.x; a2.y += p2.y; a2.z += p2.z; a2.w += p2.w;
        a3.x += p3.x; a3.y += p3.y; a3.z += p3.z; a3.w += p3.w;
    }
    int bb = bt * 16;
    sy[bb +  0][gl] = a0.x; sy[bb +  1][gl] = a0.y; sy[bb +  2][gl] = a0.z; sy[bb +  3][gl] = a0.w;
    sy[bb +  4][gl] = a1.x; sy[bb +  5][gl] = a1.y; sy[bb +  6][gl] = a1.z; sy[bb +  7][gl] = a1.w;
    sy[bb +  8][gl] = a2.x; sy[bb +  9][gl] = a2.y; sy[bb + 10][gl] = a2.z; sy[bb + 11][gl] = a2.w;
    sy[bb + 12][gl] = a3.x; sy[bb + 13][gl] = a3.y; sy[bb + 14][gl] = a3.z; sy[bb + 15][gl] = a3.w;
    __syncthreads();
    int rb = tid >> 1, half = tid & 1;
    float cv = cvec[rb];
    int cb = half * 16;
    float4 o0, o1, o2, o3;
    o0.x = sy[rb][cb + 0] + cv; o0.y = sy[rb][cb + 1] + cv; o0.z = sy[rb][cb + 2] + cv; o0.w = sy[rb][cb + 3] + cv;
    o1.x = sy[rb][cb + 4] + cv; o1.y = sy[rb][cb + 5] + cv; o1.z = sy[rb][cb + 6] + cv; o1.w = sy[rb][cb + 7] + cv;
    o2.x = sy[rb][cb + 8] + cv; o2.y = sy[rb][cb + 9] + cv; o2.z = sy[rb][cb +10] + cv; o2.w = sy[rb][cb +11] + cv;
    o3.x = sy[rb][cb +12] + cv; o3.y = sy[rb][cb +13] + cv; o3.z = sy[rb][cb +14] + cv; o3.w = sy[rb][cb +15] + cv;
    float* yp = &y[(size_t)rb * G_ + g0 + cb];
    *(float4*)&yp[0]  = o0;
    *(float4*)&yp[4]  = o1;
    *(float4*)&yp[8]  = o2;
    *(float4*)&yp[12] = o3;
}

// ---------------------------------------------------------------------------
extern "C" void kernel_launch(void* const* d_in, const int* in_sizes, int n_in,
                              void* d_out, int out_size, void* d_ws, size_t ws_size,
                              hipStream_t stream) {
    const float* ctl   = (const float*)d_in[0];
    const float* dt    = (const float*)d_in[1];
    const int*   cidx  = (const int*)d_in[2];
    // d_in[3] = drug_fp (unused)
    const float* M     = (const float*)d_in[4];
    const float* A     = (const float*)d_in[5];
    const float* W_in  = (const float*)d_in[6];
    const float* b_in  = (const float*)d_in[7];
    const float* cemb  = (const float*)d_in[8];
    const float* W_out = (const float*)d_in[9];
    const float* b_out = (const float*)d_in[10];
    float* y = (float*)d_out;

    char* ws = (char*)d_ws;
    size_t o = 0;
    auto take = [&](size_t bytes) { char* p = ws + o; o = (o + bytes + 255) & ~(size_t)255; return p; };
    unsigned short* XpT = (unsigned short*)take((size_t)512 * GP * 2);  // 12.6 MB
    unsigned short* MTb = (unsigned short*)take((size_t)K_ * GP * 2);   // 12.6 MB
    float* Cp   = (float*)take((size_t)NSEG * K_ * K_ * 4);             // 12.6 MB
    int*   rcnt = (int*)  take((size_t)G_ * 4);
    int*   rell = (int*)  take((size_t)G_ * RW * 4);                    // 1.5 MB
    float* cvec = (float*)take(B_ * 4);
    float* AT   = (float*)take((size_t)K_ * K_ * 4);                    // 1 MB each
    float* U2   = (float*)take((size_t)K_ * K_ * 4);
    float* M2   = (float*)take((size_t)K_ * K_ * 4);
    float* Yop  = (float*)take((size_t)K_ * K_ * 4);
    float* M4   = (float*)take((size_t)K_ * K_ * 4);
    float* U4   = (float*)take((size_t)K_ * K_ * 4);
    float* M8   = (float*)take((size_t)K_ * K_ * 4);
    float* U8   = (float*)take((size_t)K_ * K_ * 4);
    float* sout = (float*)take((size_t)K_ * B_ * 4);
    float* q    = (float*)take((size_t)K_ * B_ * 4);
    float* z10  = (float*)take((size_t)K_ * B_ * 4);
    (void)ws_size; (void)in_sizes; (void)n_in; (void)out_size;

    // L1: packs (XpT hi/lo, MTb) + AT/U2 + row-ELL + cvec
    k_pre<<<12473, 256, 0, stream>>>(ctl, dt, M, A, cidx, cemb, W_out, b_out,
                                     XpT, MTb, AT, U2, rcnt, rell, cvec);
    // L2: split-K MFMA GEMM (Cp) + P1 (M2, Yop)
    k_gemm<<<448, 256, 0, stream>>>(MTb, XpT, Cp, AT, U2, M2, Yop);
    // L3: reduce Cp + deg + MLP -> sout ; P2 (M4, U4)
    k_red<<<768, 256, 0, stream>>>(Cp, MTb, W_in, b_in, W_out, sout,
                                   M2, U2, M4, U4);
    // L4: P3 (M8, U8) + panel q = Yop*s   (512 mm blocks + 512 panel blocks)
    k_p3<<<1024, 256, 0, stream>>>(M4, U4, M8, U8, Yop, sout, q);
    // L5: z10 = M8*q + U8*s
    k_zfin<<<K_ / 2, 1024, 0, stream>>>(M8, U8, q, sout, z10);
    // L6: y[b,g] = cvec[b] + sum_{k in row g} z10[k][b]
    k_outs<<<G_ / 32, 256, 0, stream>>>(z10, rcnt, rell, cvec, y);
}

// Round 9
// 110.804 us; speedup vs baseline: 1.6172x; 1.0714x over previous
//
#include <hip/hip_runtime.h>

// Problem constants (match reference)
#define B_    128
#define G_    12000
#define GP    12288     // G padded to 12*1024 (pad rows are zero => exact)
#define K_    512
#define H_    64
#define NSEG  12        // GEMM split-K segments
#define SEGG  1024      // genes per segment
#define BKT   64        // GEMM K-step

typedef __attribute__((ext_vector_type(8))) short bf16x8;
typedef __attribute__((ext_vector_type(4))) float f32x4;

__device__ __forceinline__ unsigned short f2bf(float x) {
    union { float f; unsigned u; } v; v.f = x;
    unsigned r = (v.u + 0x7FFFu + ((v.u >> 16) & 1u)) >> 16;
    return (unsigned short)r;
}
__device__ __forceinline__ float bf2f(unsigned short b) {
    union { float f; unsigned u; } v; v.u = ((unsigned)b) << 16;
    return v.f;
}

// ---------------- mm body: O = alpha*Aop*Bop + beta*Cop; opt O2 = O + Dop ---
// 32x32 out tile at (k0,l0), BK=64, 256 threads, 2x2 micro. sm: 4480 floats.
__device__ __forceinline__ void mm_body(int k0, int l0, float* __restrict__ sm,
        const float* __restrict__ Aop, const float* __restrict__ Bop,
        const float* __restrict__ Cop, const float* __restrict__ Dop,
        float alpha, float beta, float* __restrict__ O, float* __restrict__ O2) {
    float (*Xa)[68] = (float(*)[68])sm;              // 32*68 = 2176 floats
    float (*Xb)[36] = (float(*)[36])(sm + 2176);     // 64*36 = 2304 floats
    int tid = threadIdx.x;
    int kg = tid & 15, lg = tid >> 4;
    float acc[2][2] = {};
    for (int jj = 0; jj < K_; jj += 64) {
#pragma unroll
        for (int i = 0; i < 2; ++i) {
            int lin = tid + i * 256;
            int r = lin >> 4, c4 = lin & 15;
            *(float4*)&Xa[r][c4 * 4] =
                *(const float4*)&Aop[(size_t)(l0 + r) * K_ + jj + c4 * 4];
        }
#pragma unroll
        for (int i = 0; i < 2; ++i) {
            int lin = tid + i * 256;
            int r = lin >> 3, c4 = lin & 7;
            *(float4*)&Xb[r][c4 * 4] =
                *(const float4*)&Bop[(size_t)(jj + r) * K_ + k0 + c4 * 4];
        }
        __syncthreads();
#pragma unroll 8
        for (int j = 0; j < 64; ++j) {
            float xa0 = Xa[lg * 2][j], xa1 = Xa[lg * 2 + 1][j];
            float xb0 = Xb[j][kg * 2], xb1 = Xb[j][kg * 2 + 1];
            acc[0][0] = fmaf(xa0, xb0, acc[0][0]);
            acc[0][1] = fmaf(xa0, xb1, acc[0][1]);
            acc[1][0] = fmaf(xa1, xb0, acc[1][0]);
            acc[1][1] = fmaf(xa1, xb1, acc[1][1]);
        }
        __syncthreads();
    }
#pragma unroll
    for (int i = 0; i < 2; ++i) {
        size_t idx = (size_t)(l0 + lg * 2 + i) * K_ + k0 + kg * 2;
        float2 v;
        v.x = alpha * acc[i][0];
        v.y = alpha * acc[i][1];
        if (beta != 0.0f) {
            float2 cc = *(const float2*)&Cop[idx];
            v.x = fmaf(beta, cc.x, v.x);
            v.y = fmaf(beta, cc.y, v.y);
        }
        *(float2*)&O[idx] = v;
        if (O2) {
            float2 dd = *(const float2*)&Dop[idx];
            float2 w2; w2.x = v.x + dd.x; w2.y = v.y + dd.y;
            *(float2*)&O2[idx] = w2;
        }
    }
}

// ========== L1 k_pre: {XpT bf16 hi/lo | MTb + Mb pack (ONE M read) |
//                       AT,U2 | cvec} ======================================
__global__ __launch_bounds__(256) void k_pre(
        const float* __restrict__ ctl, const float* __restrict__ dt,
        const float* __restrict__ M, const float* __restrict__ A,
        const int* __restrict__ cidx, const float* __restrict__ cemb,
        const float* __restrict__ W_out, const float* __restrict__ b_out,
        unsigned short* __restrict__ XpT, unsigned short* __restrict__ MTb,
        unsigned short* __restrict__ Mb,
        float* __restrict__ AT, float* __restrict__ U2,
        float* __restrict__ cvec) {
    __shared__ float t[32][33];
    int bid = blockIdx.x, tid = threadIdx.x;
    if (bid < 3072) {                          // XpT: rows p (hi) and p+256 (lo)
        int p = bid / 12, chunk = bid % 12;
        int ch = p >> 7, b = p & 127;
        const float* src = (ch ? dt : ctl) + (size_t)b * G_;
        int g = chunk * 1024 + tid * 4;
        float x0 = 0.f, x1 = 0.f, x2 = 0.f, x3 = 0.f;
        if (g + 3 < G_) {
            float4 v = *(const float4*)&src[g];
            x0 = v.x; x1 = v.y; x2 = v.z; x3 = v.w;
        } else {
            if (g + 0 < G_) x0 = src[g + 0];
            if (g + 1 < G_) x1 = src[g + 1];
            if (g + 2 < G_) x2 = src[g + 2];
            if (g + 3 < G_) x3 = src[g + 3];
        }
        unsigned short h0 = f2bf(x0), h1 = f2bf(x1), h2 = f2bf(x2), h3 = f2bf(x3);
        ushort4 hv; hv.x = h0; hv.y = h1; hv.z = h2; hv.w = h3;
        *(ushort4*)&XpT[(size_t)p * GP + g] = hv;
        ushort4 lv;
        lv.x = f2bf(x0 - bf2f(h0)); lv.y = f2bf(x1 - bf2f(h1));
        lv.z = f2bf(x2 - bf2f(h2)); lv.w = f2bf(x3 - bf2f(h3));
        *(ushort4*)&XpT[(size_t)(p + 256) * GP + g] = lv;
    } else if (bid < 9216) {                   // MTb[k][g] + Mb[g][k] from one read
        int id = bid - 3072;
        int gt = id % 384, kt = id / 384;
        int g0 = gt * 32, k0 = kt * 32;
        int tx = tid & 31, ty = tid >> 5;
#pragma unroll
        for (int j = 0; j < 4; ++j) {
            int g = g0 + ty + 8 * j;
            float v = (g < G_) ? M[(size_t)g * K_ + k0 + tx] : 0.0f;
            t[ty + 8 * j][tx] = v;
            Mb[(size_t)g * K_ + k0 + tx] = f2bf(v);   // non-transposed pack
        }
        __syncthreads();
#pragma unroll
        for (int j = 0; j < 4; ++j)
            MTb[(size_t)(k0 + ty + 8 * j) * GP + g0 + tx] = f2bf(t[tx][ty + 8 * j]);
    } else if (bid < 9472) {                   // AT + U2 = 0.09*AT + 0.1*I
        int id = bid - 9216;
        int x0 = (id & 15) * 32, y0 = (id >> 4) * 32;
        int tx = tid & 31, ty = tid >> 5;
#pragma unroll
        for (int j = 0; j < 4; ++j)
            t[ty + 8 * j][tx] = A[(size_t)(y0 + ty + 8 * j) * K_ + x0 + tx];
        __syncthreads();
#pragma unroll
        for (int j = 0; j < 4; ++j) {
            int row = x0 + ty + 8 * j, col = y0 + tx;
            float v = t[tx][ty + 8 * j];
            AT[(size_t)row * K_ + col] = v;
            U2[(size_t)row * K_ + col] = 0.09f * v + (row == col ? 0.1f : 0.0f);
        }
    } else {                                   // cvec
        if (tid < B_) {
            int ci = cidx[tid];
            float acc = b_out[0];
#pragma unroll 8
            for (int h = 0; h < H_; ++h)
                acc = fmaf(cemb[ci * H_ + h], W_out[h], acc);
            cvec[tid] = acc;
        }
    }
}

// ========== L2 k_gemm: {Cp[seg] = MTb*XpT^T (MFMA, split-K) | P1 mm} ========
__global__ __launch_bounds__(256) void k_gemm(
        const unsigned short* __restrict__ MTb, const unsigned short* __restrict__ XpT,
        float* __restrict__ Cp,
        const float* __restrict__ AT, const float* __restrict__ U2,
        float* __restrict__ M2, float* __restrict__ Yop) {
    __shared__ __align__(16) char smraw[36864];
    int bid = blockIdx.x, tid = threadIdx.x;
    if (bid < 192) {
        unsigned short (*Al)[72] = (unsigned short(*)[72])smraw;           // 128x72
        unsigned short (*Bl)[72] = (unsigned short(*)[72])(smraw + 18432); // 128x72
        int tile = bid & 15, seg = bid >> 4;
        int m0 = (tile & 3) * 128, n0 = (tile >> 2) * 128;
        size_t gbase = (size_t)seg * SEGG;
        int wid = tid >> 6, lane = tid & 63;
        int wm = (wid >> 1) * 64, wn = (wid & 1) * 64;
        int r16 = lane & 15, kg8 = (lane >> 4) * 8;
        int ld_row = tid >> 3, ld_c8 = (tid & 7) * 8;
        f32x4 acc[4][4] = {};
        for (int kk = 0; kk < SEGG; kk += BKT) {
#pragma unroll
            for (int i = 0; i < 4; ++i) {
                int r = ld_row + 32 * i;
                *(uint4*)&Al[r][ld_c8] =
                    *(const uint4*)&MTb[(size_t)(m0 + r) * GP + gbase + kk + ld_c8];
                *(uint4*)&Bl[r][ld_c8] =
                    *(const uint4*)&XpT[(size_t)(n0 + r) * GP + gbase + kk + ld_c8];
            }
            __syncthreads();
#pragma unroll
            for (int ks = 0; ks < 2; ++ks) {
                bf16x8 af[4], bf[4];
#pragma unroll
                for (int mi = 0; mi < 4; ++mi)
                    af[mi] = *(const bf16x8*)&Al[wm + mi * 16 + r16][ks * 32 + kg8];
#pragma unroll
                for (int ni = 0; ni < 4; ++ni)
                    bf[ni] = *(const bf16x8*)&Bl[wn + ni * 16 + r16][ks * 32 + kg8];
#pragma unroll
                for (int mi = 0; mi < 4; ++mi)
#pragma unroll
                    for (int ni = 0; ni < 4; ++ni)
                        acc[mi][ni] = __builtin_amdgcn_mfma_f32_16x16x32_bf16(
                            af[mi], bf[ni], acc[mi][ni], 0, 0, 0);
            }
            __syncthreads();
        }
        float* C = Cp + (size_t)seg * (K_ * K_);
        int cr = (lane >> 4) * 4, cc = lane & 15;
#pragma unroll
        for (int mi = 0; mi < 4; ++mi)
#pragma unroll
            for (int ni = 0; ni < 4; ++ni) {
                size_t rb = (size_t)(m0 + wm + mi * 16 + cr) * K_
                          + (n0 + wn + ni * 16 + cc);
#pragma unroll
                for (int r = 0; r < 4; ++r)
                    C[rb + (size_t)r * K_] = acc[mi][ni][r];
            }
    } else {                                   // P1: M2 = 0.81*AT*AT; Yop = M2+U2
        int id = bid - 192;
        mm_body((id & 15) * 32, (id >> 4) * 32, (float*)smraw,
                AT, AT, nullptr, U2, 0.81f, 0.0f, M2, Yop);
    }
}

// ========== L3 k_red: {reduce Cp + deg (vectorized) + MLP | P2: M4, U4} =====
__global__ __launch_bounds__(256) void k_red(
        const float* __restrict__ Cp, const unsigned short* __restrict__ MTb,
        const float* __restrict__ W_in, const float* __restrict__ b_in,
        const float* __restrict__ W_out, float* __restrict__ sout,
        const float* __restrict__ M2, const float* __restrict__ U2,
        float* __restrict__ M4, float* __restrict__ U4) {
    __shared__ __align__(16) float sm[4480];
    int bid = blockIdx.x, tid = threadIdx.x;
    if (bid < 256) {
        int kloc = tid >> 7, b = tid & 127;
        int k = bid * 2 + kloc;
        // degree = nnz of MTb row k, ushort8 vector loads (pad rows are zero)
        int cnt = 0;
        const unsigned short* mrow = MTb + (size_t)k * GP;
#pragma unroll
        for (int i = 0; i < 12; ++i) {
            uint4 v = *(const uint4*)&mrow[i * 1024 + b * 8];
            cnt += ((v.x & 0xFFFFu) != 0) + ((v.x >> 16) != 0);
            cnt += ((v.y & 0xFFFFu) != 0) + ((v.y >> 16) != 0);
            cnt += ((v.z & 0xFFFFu) != 0) + ((v.z >> 16) != 0);
            cnt += ((v.w & 0xFFFFu) != 0) + ((v.w >> 16) != 0);
        }
#pragma unroll
        for (int off = 32; off; off >>= 1) cnt += __shfl_down(cnt, off, 64);
        __shared__ int dsum[4];
        __shared__ float degs[2];
        int wv = tid >> 6;
        if ((tid & 63) == 0) dsum[wv] = cnt;
        __syncthreads();
        if (tid < 2) degs[tid] = (float)(dsum[tid * 2] + dsum[tid * 2 + 1]);
        __syncthreads();
        float x0 = 0.f, x1 = 0.f;
        for (int s = 0; s < NSEG; ++s) {
            const float* Cb = Cp + (size_t)s * (K_ * K_) + (size_t)k * K_;
            x0 += Cb[b]       + Cb[256 + b];
            x1 += Cb[128 + b] + Cb[384 + b];
        }
        float inv = 1.0f / fmaxf(degs[kloc], 1.0f);
        x0 *= inv; x1 *= inv;
        float s = 0.f;
#pragma unroll 8
        for (int h = 0; h < H_; ++h) {
            float v = fmaf(x0, W_in[h], fmaf(x1, W_in[H_ + h], b_in[h]));
            v = fmaxf(v, 0.f);
            s = fmaf(v, W_out[h], s);
        }
        sout[k * B_ + b] = s;
    } else {                                   // P2: M4 = M2*M2; U4 = M2*U2+U2
        int id = bid - 256;
        int t = id & 255;
        if (id < 256)
            mm_body((t & 15) * 32, (t >> 4) * 32, sm, M2, M2, nullptr, nullptr,
                    1.0f, 0.0f, M4, nullptr);
        else
            mm_body((t & 15) * 32, (t >> 4) * 32, sm, M2, U2, U2, nullptr,
                    1.0f, 1.0f, U4, nullptr);
    }
}

// ========== L4 k_p3: {P3: M8 = M4*M4, U8 = M4*U4+U4 | panel q = Yop*s} ======
__global__ __launch_bounds__(256) void k_p3(
        const float* __restrict__ M4, const float* __restrict__ U4,
        float* __restrict__ M8, float* __restrict__ U8,
        const float* __restrict__ Yop, const float* __restrict__ sout,
        float* __restrict__ q) {
    __shared__ __align__(16) float sm[4480];
    int bid = blockIdx.x, tid = threadIdx.x;
    if (bid < 512) {
        int t = bid & 255;
        if (bid < 256)
            mm_body((t & 15) * 32, (t >> 4) * 32, sm, M4, M4, nullptr, nullptr,
                    1.0f, 0.0f, M8, nullptr);
        else
            mm_body((t & 15) * 32, (t >> 4) * 32, sm, M4, U4, U4, nullptr,
                    1.0f, 1.0f, U8, nullptr);
    } else {                                   // q[l][b] = sum_k Yop[l][k] s[k][b]
        int l = bid - 512;                     // 0..511
        float* Wr  = sm;                       // 512 floats
        float* red = sm + 512;                 // 256 floats
        if (tid < 128)
            ((float4*)Wr)[tid] = ((const float4*)&Yop[(size_t)l * K_])[tid];
        __syncthreads();
        int b = tid & 127, seg = tid >> 7;     // 2 segs x 256 k
        int kb = seg * 256;
        float a0 = 0.f, a1 = 0.f, a2 = 0.f, a3 = 0.f;
#pragma unroll 4
        for (int kk = 0; kk < 256; kk += 4) {
            int k = kb + kk;
            a0 = fmaf(Wr[k + 0], sout[(k + 0) * B_ + b], a0);
            a1 = fmaf(Wr[k + 1], sout[(k + 1) * B_ + b], a1);
            a2 = fmaf(Wr[k + 2], sout[(k + 2) * B_ + b], a2);
            a3 = fmaf(Wr[k + 3], sout[(k + 3) * B_ + b], a3);
        }
        red[seg * 128 + b] = (a0 + a1) + (a2 + a3);
        __syncthreads();
        if (tid < 128)
            q[l * B_ + b] = red[b] + red[128 + b];
    }
}

// ========== L5 k_zfin: z10 = M8*q + U8*s -> zbT bf16 hi/lo [B][2K] ==========
__global__ __launch_bounds__(1024) void k_zfin(
        const float* __restrict__ M8, const float* __restrict__ U8,
        const float* __restrict__ q, const float* __restrict__ sout,
        unsigned short* __restrict__ zbT) {
    __shared__ __align__(16) float Wr[4 * K_];   // M8 row0,1 | U8 row0,1
    __shared__ float red[8][2][128];
    int tid = threadIdx.x;
    int l0 = blockIdx.x * 2;
    if (tid < 256)
        ((float4*)Wr)[tid] = ((const float4*)&M8[(size_t)l0 * K_])[tid];
    else if (tid < 512)
        ((float4*)&Wr[2 * K_])[tid - 256] =
            ((const float4*)&U8[(size_t)l0 * K_])[tid - 256];
    __syncthreads();
    int b = tid & 127, seg = tid >> 7;           // 8 segs x 64 k
    int kb = seg * 64;
    float a0m = 0.f, a0u = 0.f, a1m = 0.f, a1u = 0.f;
#pragma unroll 8
    for (int kk = 0; kk < 64; ++kk) {
        int k = kb + kk;
        float qv = q[k * B_ + b];
        float sv = sout[k * B_ + b];
        a0m = fmaf(Wr[k], qv, a0m);
        a0u = fmaf(Wr[2 * K_ + k], sv, a0u);
        a1m = fmaf(Wr[K_ + k], qv, a1m);
        a1u = fmaf(Wr[3 * K_ + k], sv, a1u);
    }
    red[seg][0][b] = a0m + a0u;
    red[seg][1][b] = a1m + a1u;
    __syncthreads();
    if (tid < 256) {
        int row = tid >> 7, bb = tid & 127;
        float t = 0.f;
#pragma unroll
        for (int u = 0; u < 8; ++u) t += red[u][row][bb];
        unsigned short hi = f2bf(t);
        unsigned short lo = f2bf(t - bf2f(hi));
        zbT[(size_t)bb * (2 * K_) + (l0 + row)]      = hi;   // hi plane
        zbT[(size_t)bb * (2 * K_) + K_ + (l0 + row)] = lo;   // lo plane
    }
}

// ========== L6 k_yg: y[b][g] = sum_k Mb[g][k]*(zhi+zlo)[k][b] + cvec[b] =====
// MFMA: A = Mb rows (g, k contiguous), B = zbT rows (b, k contiguous), A*B^T.
__global__ __launch_bounds__(256) void k_yg(
        const unsigned short* __restrict__ Mb, const unsigned short* __restrict__ zbT,
        const float* __restrict__ cvec, float* __restrict__ y) {
    __shared__ __align__(16) unsigned short Al[128][72];
    __shared__ __align__(16) unsigned short Bh[128][72];
    __shared__ __align__(16) unsigned short Bl2[128][72];
    int tid = threadIdx.x;
    int g0 = blockIdx.x * 128;
    int wid = tid >> 6, lane = tid & 63;
    int wm = (wid >> 1) * 64, wn = (wid & 1) * 64;
    int r16 = lane & 15, kg8 = (lane >> 4) * 8;
    int ld_row = tid >> 3, ld_c8 = (tid & 7) * 8;
    f32x4 acc[4][4] = {};
    for (int kk = 0; kk < K_; kk += BKT) {
#pragma unroll
        for (int i = 0; i < 4; ++i) {
            int r = ld_row + 32 * i;
            *(uint4*)&Al[r][ld_c8] =
                *(const uint4*)&Mb[(size_t)(g0 + r) * K_ + kk + ld_c8];
            *(uint4*)&Bh[r][ld_c8] =
                *(const uint4*)&zbT[(size_t)r * (2 * K_) + kk + ld_c8];
            *(uint4*)&Bl2[r][ld_c8] =
                *(const uint4*)&zbT[(size_t)r * (2 * K_) + K_ + kk + ld_c8];
        }
        __syncthreads();
#pragma unroll
        for (int ks = 0; ks < 2; ++ks) {
            bf16x8 af[4], bh[4], bl[4];
#pragma unroll
            for (int mi = 0; mi < 4; ++mi)
                af[mi] = *(const bf16x8*)&Al[wm + mi * 16 + r16][ks * 32 + kg8];
#pragma unroll
            for (int ni = 0; ni < 4; ++ni) {
                bh[ni] = *(const bf16x8*)&Bh[wn + ni * 16 + r16][ks * 32 + kg8];
                bl[ni] = *(const bf16x8*)&Bl2[wn + ni * 16 + r16][ks * 32 + kg8];
            }
#pragma unroll
            for (int mi = 0; mi < 4; ++mi)
#pragma unroll
                for (int ni = 0; ni < 4; ++ni) {
                    acc[mi][ni] = __builtin_amdgcn_mfma_f32_16x16x32_bf16(
                        af[mi], bh[ni], acc[mi][ni], 0, 0, 0);
                    acc[mi][ni] = __builtin_amdgcn_mfma_f32_16x16x32_bf16(
                        af[mi], bl[ni], acc[mi][ni], 0, 0, 0);
                }
        }
        __syncthreads();
    }
    // C[m=g][n=b]: per lane, reg r -> g = base+r (4 consecutive), col -> b.
    int cr = (lane >> 4) * 4, cc = lane & 15;
#pragma unroll
    for (int ni = 0; ni < 4; ++ni) {
        int b = wn + ni * 16 + cc;
        float cv = cvec[b];
#pragma unroll
        for (int mi = 0; mi < 4; ++mi) {
            int g = g0 + wm + mi * 16 + cr;
            if (g < G_) {                      // 4-aligned; whole float4 valid
                float4 o;
                o.x = acc[mi][ni][0] + cv;
                o.y = acc[mi][ni][1] + cv;
                o.z = acc[mi][ni][2] + cv;
                o.w = acc[mi][ni][3] + cv;
                *(float4*)&y[(size_t)b * G_ + g] = o;
            }
        }
    }
}

// ---------------------------------------------------------------------------
extern "C" void kernel_launch(void* const* d_in, const int* in_sizes, int n_in,
                              void* d_out, int out_size, void* d_ws, size_t ws_size,
                              hipStream_t stream) {
    const float* ctl   = (const float*)d_in[0];
    const float* dt    = (const float*)d_in[1];
    const int*   cidx  = (const int*)d_in[2];
    // d_in[3] = drug_fp (unused)
    const float* M     = (const float*)d_in[4];
    const float* A     = (const float*)d_in[5];
    const float* W_in  = (const float*)d_in[6];
    const float* b_in  = (const float*)d_in[7];
    const float* cemb  = (const float*)d_in[8];
    const float* W_out = (const float*)d_in[9];
    const float* b_out = (const float*)d_in[10];
    float* y = (float*)d_out;

    char* ws = (char*)d_ws;
    size_t o = 0;
    auto take = [&](size_t bytes) { char* p = ws + o; o = (o + bytes + 255) & ~(size_t)255; return p; };
    unsigned short* XpT = (unsigned short*)take((size_t)512 * GP * 2);  // 12.6 MB
    unsigned short* MTb = (unsigned short*)take((size_t)K_ * GP * 2);   // 12.6 MB
    unsigned short* Mb  = (unsigned short*)take((size_t)GP * K_ * 2);   // 12.6 MB
    unsigned short* zbT = (unsigned short*)take((size_t)B_ * 2 * K_ * 2); // 256 KB
    float* Cp   = (float*)take((size_t)NSEG * K_ * K_ * 4);             // 12.6 MB
    float* cvec = (float*)take(B_ * 4);
    float* AT   = (float*)take((size_t)K_ * K_ * 4);                    // 1 MB each
    float* U2   = (float*)take((size_t)K_ * K_ * 4);
    float* M2   = (float*)take((size_t)K_ * K_ * 4);
    float* Yop  = (float*)take((size_t)K_ * K_ * 4);
    float* M4   = (float*)take((size_t)K_ * K_ * 4);
    float* U4   = (float*)take((size_t)K_ * K_ * 4);
    float* M8   = (float*)take((size_t)K_ * K_ * 4);
    float* U8   = (float*)take((size_t)K_ * K_ * 4);
    float* sout = (float*)take((size_t)K_ * B_ * 4);
    float* q    = (float*)take((size_t)K_ * B_ * 4);
    (void)ws_size; (void)in_sizes; (void)n_in; (void)out_size;

    // L1: packs (XpT hi/lo, MTb+Mb from ONE M read) + AT/U2 + cvec
    k_pre<<<9473, 256, 0, stream>>>(ctl, dt, M, A, cidx, cemb, W_out, b_out,
                                    XpT, MTb, Mb, AT, U2, cvec);
    // L2: split-K MFMA GEMM (Cp) + P1 (M2, Yop)
    k_gemm<<<448, 256, 0, stream>>>(MTb, XpT, Cp, AT, U2, M2, Yop);
    // L3: reduce Cp + deg + MLP -> sout ; P2 (M4, U4)
    k_red<<<768, 256, 0, stream>>>(Cp, MTb, W_in, b_in, W_out, sout,
                                   M2, U2, M4, U4);
    // L4: P3 (M8, U8) + panel q = Yop*s
    k_p3<<<1024, 256, 0, stream>>>(M4, U4, M8, U8, Yop, sout, q);
    // L5: z10 = M8*q + U8*s -> zbT bf16 hi/lo
    k_zfin<<<K_ / 2, 1024, 0, stream>>>(M8, U8, q, sout, zbT);
    // L6: y = Mb * (zhi + zlo) + cvec   (MFMA)
    k_yg<<<(G_ + 127) / 128, 256, 0, stream>>>(Mb, zbT, cvec, y);
}